// Round 6
// baseline (476.799 us; speedup 1.0000x reference)
//
#include <hip/hip_runtime.h>
#include <hip/hip_bf16.h>
#include <cstdint>
#include <cstddef>

#define NN 50000
#define EE 800000
#define EP (EE + NN)   // 850000 edges incl. appended self-loops
#define DD 128
#define NEG 0.2f
#define EPSL 1e-5f
#define CHUNK 512

typedef __hip_bfloat16 bf16;

__device__ inline float wave_reduce_sum(float v) {
    for (int off = 32; off; off >>= 1) v += __shfl_xor(v, off);
    return v;
}
__device__ inline float bflo(unsigned u) { return __uint_as_float(u << 16); }
__device__ inline float bfhi(unsigned u) { return __uint_as_float(u & 0xffff0000u); }

__device__ inline void store4(float* Out, size_t idx, float4 v) {
    *(float4*)&Out[idx] = v;
}
__device__ inline void store4(bf16* Out, size_t idx, float4 v) {
    union { bf16 b[4]; ushort4 u; } cv;
    cv.b[0] = (bf16)v.x; cv.b[1] = (bf16)v.y; cv.b[2] = (bf16)v.z; cv.b[3] = (bf16)v.w;
    *(ushort4*)&Out[idx] = cv.u;
}

// ---------------- CSR build ----------------

__global__ __launch_bounds__(256) void hist_kernel(const int* __restrict__ ei,
                                                   int* __restrict__ deg) {
    int i = blockIdx.x * 256 + threadIdx.x;
    if (i >= EP) return;
    int dst = (i < EE) ? ei[EE + i] : (i - EE);
    atomicAdd(&deg[dst], 1);
}

// single-block exclusive scan over deg[0..NN) -> row_ptr, cursor (int4 + shuffle)
__global__ __launch_bounds__(1024) void scan_kernel(const int* __restrict__ deg,
                                                    int* __restrict__ row_ptr,
                                                    int* __restrict__ cursor) {
    __shared__ int wsum[16];
    __shared__ int carry_s;
    int tid = threadIdx.x, lane = tid & 63, wv = tid >> 6;  // 16 waves
    if (tid == 0) carry_s = 0;
    __syncthreads();
    for (int base = 0; base < NN; base += 4096) {
        int i4 = base + tid * 4;
        int4 v;
        if (i4 + 3 < NN) v = *(const int4*)&deg[i4];
        else {
            v.x = (i4 + 0 < NN) ? deg[i4 + 0] : 0;
            v.y = (i4 + 1 < NN) ? deg[i4 + 1] : 0;
            v.z = (i4 + 2 < NN) ? deg[i4 + 2] : 0;
            v.w = (i4 + 3 < NN) ? deg[i4 + 3] : 0;
        }
        int tsum = v.x + v.y + v.z + v.w;
        int x = tsum;
        for (int off = 1; off < 64; off <<= 1) {
            int t = __shfl_up(x, off);
            if (lane >= off) x += t;
        }
        if (lane == 63) wsum[wv] = x;
        __syncthreads();
        if (wv == 0) {
            int s = (lane < 16) ? wsum[lane] : 0;
            for (int off = 1; off < 16; off <<= 1) {
                int t = __shfl_up(s, off);
                if (lane >= off) s += t;
            }
            if (lane < 16) wsum[lane] = s;
        }
        __syncthreads();
        int waveoff = (wv == 0) ? 0 : wsum[wv - 1];
        int carry = carry_s;
        int o0 = carry + waveoff + x - tsum;
        int o1 = o0 + v.x, o2 = o1 + v.y, o3 = o2 + v.z;
        if (i4 + 3 < NN) {
            int4 o = make_int4(o0, o1, o2, o3);
            *(int4*)&row_ptr[i4] = o;
            *(int4*)&cursor[i4] = o;
        } else {
            if (i4 + 0 < NN) { row_ptr[i4 + 0] = o0; cursor[i4 + 0] = o0; }
            if (i4 + 1 < NN) { row_ptr[i4 + 1] = o1; cursor[i4 + 1] = o1; }
            if (i4 + 2 < NN) { row_ptr[i4 + 2] = o2; cursor[i4 + 2] = o2; }
            if (i4 + 3 < NN) { row_ptr[i4 + 3] = o3; cursor[i4 + 3] = o3; }
        }
        __syncthreads();
        if (tid == 0) carry_s += wsum[15];
        __syncthreads();
    }
    if (tid == 0) row_ptr[NN] = carry_s;
}

__global__ __launch_bounds__(256) void scatter_kernel(const int* __restrict__ ei,
                                                      int* __restrict__ cursor,
                                                      int* __restrict__ col) {
    int i = blockIdx.x * 256 + threadIdx.x;
    if (i >= EP) return;
    int s, dst; unsigned flag;
    if (i < EE) { s = ei[i]; dst = ei[EE + i]; flag = 0u; }
    else        { s = i - EE; dst = s; flag = 0x80000000u; }  // appended self-loop
    int pos = atomicAdd(&cursor[dst], 1);
    col[pos] = (int)((unsigned)s | flag);
}

// ---------------- GEMM (+optional fused LN1+relu on input) + attention dots ----------------
// 16 rows per block (50000 = 16*3125); inner loop k-vectorized x4 (ds_read_b128)
template <int H, bool LN>
__global__ __launch_bounds__(128) void gemm_attn(const float* __restrict__ X,
                                                 const float* __restrict__ W,
                                                 const float* __restrict__ att_s,
                                                 const float* __restrict__ att_d,
                                                 const double* __restrict__ stats,
                                                 const float* __restrict__ lnw,
                                                 const float* __restrict__ lnb,
                                                 bf16* __restrict__ Hout,
                                                 float* __restrict__ a_src,
                                                 float* __restrict__ a_dst) {
    const int ROWS = 16;
    int tid = threadIdx.x, lane = tid & 63, wave = tid >> 6;
    __shared__ float xs[ROWS][DD];
    __shared__ float ps_s[ROWS][2], ps_d[ROWS][2];
    int row0 = blockIdx.x * ROWS;

    float mean = 0.f, inv = 1.f, wc = 1.f, bc = 0.f;
    if (LN) {
        const double M = (double)NN * DD;
        double mean_d = stats[0] / M;
        double var_d = stats[1] / M - mean_d * mean_d;
        mean = (float)mean_d;
        inv = rsqrtf((float)var_d + EPSL);
        wc = lnw[tid]; bc = lnb[tid];
    }
    #pragma unroll
    for (int r = 0; r < ROWS; ++r) {
        float v = X[(size_t)(row0 + r) * DD + tid];
        if (LN) v = fmaxf((v - mean) * inv * wc + bc, 0.f);
        xs[r][tid] = v;
    }
    __syncthreads();
    float acc[ROWS] = {0.f};
    for (int k4 = 0; k4 < DD / 4; ++k4) {
        float w0 = W[(size_t)(4 * k4 + 0) * DD + tid];
        float w1 = W[(size_t)(4 * k4 + 1) * DD + tid];
        float w2 = W[(size_t)(4 * k4 + 2) * DD + tid];
        float w3 = W[(size_t)(4 * k4 + 3) * DD + tid];
        #pragma unroll
        for (int r = 0; r < ROWS; ++r) {
            float4 xv = *(const float4*)&xs[r][k4 * 4];
            acc[r] = fmaf(xv.x, w0, acc[r]);
            acc[r] = fmaf(xv.y, w1, acc[r]);
            acc[r] = fmaf(xv.z, w2, acc[r]);
            acc[r] = fmaf(xv.w, w3, acc[r]);
        }
    }
    float as = att_s[tid], ad = att_d[tid];
    #pragma unroll
    for (int r = 0; r < ROWS; ++r) {
        Hout[(size_t)(row0 + r) * DD + tid] = (bf16)acc[r];
        float psum = wave_reduce_sum(acc[r] * as);
        float pdum = wave_reduce_sum(acc[r] * ad);
        if (lane == 0) { ps_s[r][wave] = psum; ps_d[r][wave] = pdum; }
    }
    __syncthreads();
    if (tid < ROWS) {
        int row = row0 + tid;
        if (H == 2) {
            a_src[row * 2 + 0] = ps_s[tid][0];
            a_src[row * 2 + 1] = ps_s[tid][1];
            a_dst[row * 2 + 0] = ps_d[tid][0];
            a_dst[row * 2 + 1] = ps_d[tid][1];
        } else {
            a_src[row] = ps_s[tid][0] + ps_s[tid][1];
            a_dst[row] = ps_d[tid][0] + ps_d[tid][1];
        }
    }
}

// ---------------- fused GAT softmax + aggregate (+per-block LN partials) ------------------
// No max-subtraction: scores here are bounded (|e| < ~12), softmax is shift-invariant.
// Single staging pass computes exp weights directly. 4 half-waves own one edge each;
// each lane owns 4 consecutive channels (uint2 = 4 bf16 per gather).
template <int H, typename OT>
__global__ __launch_bounds__(128) void gat_agg(const int* __restrict__ row_ptr,
                                               const int* __restrict__ col,
                                               const bf16* __restrict__ Hin,
                                               const float* __restrict__ a_src,
                                               const float* __restrict__ a_dst,
                                               const float* __restrict__ bias,
                                               OT* __restrict__ Out,
                                               float2* __restrict__ pstats) {
    int n = blockIdx.x;
    int tid = threadIdx.x, lane = tid & 63, wave = tid >> 6;
    int hw = tid >> 5;            // half-wave 0..3
    int sl = lane & 31;           // sub-lane in half-wave
    int c0 = sl * 4;              // 4 channels per lane
    const int head4 = (H == 2) ? (sl >> 4) : 0;  // head of this lane's channels

    int beg = row_ptr[n], end = row_ptr[n + 1];
    int deg = end - beg;

    __shared__ int   s_src[CHUNK];
    __shared__ float s_w[H][CHUNK];
    __shared__ float s_red[8];
    __shared__ float s_acc[2][DD];

    float ad0 = a_dst[n * H + 0];
    float ad1 = (H == 2) ? a_dst[n * H + 1] : 0.f;

    const ushort* Hp = (const ushort*)Hin + c0;

    float dloc0 = 0.f, dloc1 = 0.f;
    float acc[4] = {0.f, 0.f, 0.f, 0.f};

    for (int cbase = 0; cbase < deg; cbase += CHUNK) {
        int cn = min(CHUNK, deg - cbase);
        __syncthreads();  // protect LDS reuse across chunks
        // ---- single staging pass: src index + exp weights ----
        for (int i = tid; i < cn; i += 128) {
            int s = col[beg + cbase + i] & 0x7fffffff;
            s_src[i] = s;
            if (H == 2) {
                float2 av = *(const float2*)&a_src[s * 2];
                float e0 = av.x + ad0; e0 = (e0 > 0.f) ? e0 : NEG * e0;
                float e1 = av.y + ad1; e1 = (e1 > 0.f) ? e1 : NEG * e1;
                float w0 = __expf(e0), w1 = __expf(e1);
                s_w[0][i] = w0; s_w[1][i] = w1;
                dloc0 += w0; dloc1 += w1;
            } else {
                float e0 = a_src[s] + ad0; e0 = (e0 > 0.f) ? e0 : NEG * e0;
                float w0 = __expf(e0);
                s_w[0][i] = w0;
                dloc0 += w0;
            }
        }
        __syncthreads();
        // ---- accumulate: half-wave hw takes edges hw, hw+4, ... ----
        const float* wrow = s_w[head4];
        int i = hw;
        for (; i + 12 < cn; i += 16) {
            int a0 = s_src[i], a1 = s_src[i + 4], a2 = s_src[i + 8], a3 = s_src[i + 12];
            float w0 = wrow[i], w1 = wrow[i + 4], w2 = wrow[i + 8], w3 = wrow[i + 12];
            uint2 h0 = *(const uint2*)(Hp + (size_t)a0 * DD);
            uint2 h1 = *(const uint2*)(Hp + (size_t)a1 * DD);
            uint2 h2 = *(const uint2*)(Hp + (size_t)a2 * DD);
            uint2 h3 = *(const uint2*)(Hp + (size_t)a3 * DD);
            acc[0] = fmaf(w0, bflo(h0.x), acc[0]); acc[1] = fmaf(w0, bfhi(h0.x), acc[1]);
            acc[2] = fmaf(w0, bflo(h0.y), acc[2]); acc[3] = fmaf(w0, bfhi(h0.y), acc[3]);
            acc[0] = fmaf(w1, bflo(h1.x), acc[0]); acc[1] = fmaf(w1, bfhi(h1.x), acc[1]);
            acc[2] = fmaf(w1, bflo(h1.y), acc[2]); acc[3] = fmaf(w1, bfhi(h1.y), acc[3]);
            acc[0] = fmaf(w2, bflo(h2.x), acc[0]); acc[1] = fmaf(w2, bfhi(h2.x), acc[1]);
            acc[2] = fmaf(w2, bflo(h2.y), acc[2]); acc[3] = fmaf(w2, bfhi(h2.y), acc[3]);
            acc[0] = fmaf(w3, bflo(h3.x), acc[0]); acc[1] = fmaf(w3, bfhi(h3.x), acc[1]);
            acc[2] = fmaf(w3, bflo(h3.y), acc[2]); acc[3] = fmaf(w3, bfhi(h3.y), acc[3]);
        }
        for (; i < cn; i += 4) {
            int s = s_src[i];
            float w = wrow[i];
            uint2 hv = *(const uint2*)(Hp + (size_t)s * DD);
            acc[0] = fmaf(w, bflo(hv.x), acc[0]); acc[1] = fmaf(w, bfhi(hv.x), acc[1]);
            acc[2] = fmaf(w, bflo(hv.y), acc[2]); acc[3] = fmaf(w, bfhi(hv.y), acc[3]);
        }
    }

    // ---- combine half-waves within wave, then across waves via LDS ----
    #pragma unroll
    for (int j = 0; j < 4; ++j) acc[j] += __shfl_xor(acc[j], 32);
    if (lane < 32) *(float4*)&s_acc[wave][c0] = make_float4(acc[0], acc[1], acc[2], acc[3]);

    float d0 = wave_reduce_sum(dloc0);
    float d1 = (H == 2) ? wave_reduce_sum(dloc1) : 0.f;
    if (lane == 0) { s_red[wave] = d0; if (H == 2) s_red[2 + wave] = d1; }
    __syncthreads();
    float den_h0 = s_red[0] + s_red[1];
    float den_h1 = (H == 2) ? (s_red[2] + s_red[3]) : 0.f;

    if (wave == 0 && lane < 32) {
        float den = (H == 2 && head4 == 1) ? den_h1 : den_h0;
        float rinv = 1.f / (den + 1e-16f);
        float4 bi = *(const float4*)&bias[c0];
        float4 o;
        o.x = (s_acc[0][c0 + 0] + s_acc[1][c0 + 0]) * rinv + bi.x;
        o.y = (s_acc[0][c0 + 1] + s_acc[1][c0 + 1]) * rinv + bi.y;
        o.z = (s_acc[0][c0 + 2] + s_acc[1][c0 + 2]) * rinv + bi.z;
        o.w = (s_acc[0][c0 + 3] + s_acc[1][c0 + 3]) * rinv + bi.w;
        store4(Out, (size_t)n * DD + c0, o);
        // LN partials over the node's 128 outputs
        float t1 = o.x + o.y + o.z + o.w;
        float t2 = o.x * o.x + o.y * o.y + o.z * o.z + o.w * o.w;
        for (int off = 16; off; off >>= 1) {
            t1 += __shfl_xor(t1, off);
            t2 += __shfl_xor(t2, off);
        }
        if (lane == 0) pstats[n] = make_float2(t1, t2);
    }
}

// ---------------- deterministic single-block reduce of per-node LN partials ----------------
__global__ __launch_bounds__(1024) void reduce_stats_kernel(const float2* __restrict__ pstats,
                                                            double* __restrict__ stats) {
    int tid = threadIdx.x, lane = tid & 63, wv = tid >> 6;
    double s1 = 0.0, s2 = 0.0;
    for (int i = tid; i < NN; i += 1024) {
        float2 v = pstats[i];
        s1 += (double)v.x; s2 += (double)v.y;
    }
    for (int off = 32; off; off >>= 1) {
        s1 += __shfl_xor(s1, off);
        s2 += __shfl_xor(s2, off);
    }
    __shared__ double w1[16], w2[16];
    if (lane == 0) { w1[wv] = s1; w2[wv] = s2; }
    __syncthreads();
    if (tid == 0) {
        double a = 0.0, b = 0.0;
        for (int i = 0; i < 16; ++i) { a += w1[i]; b += w2[i]; }
        stats[0] = a; stats[1] = b;
    }
}

// ---------------- SimpleConv(mean, ORIGINAL edges) + fused LN2 affine + residual + relu ----
__global__ __launch_bounds__(128) void simpleconv_kernel(const int* __restrict__ row_ptr,
                                                         const int* __restrict__ col,
                                                         const bf16* __restrict__ Hin,
                                                         const float* __restrict__ X,
                                                         const double* __restrict__ stats,
                                                         const float* __restrict__ lnw,
                                                         const float* __restrict__ lnb,
                                                         float* __restrict__ Out) {
    int n = blockIdx.x;
    int tid = threadIdx.x, lane = tid & 63, wave = tid >> 6;
    int hw = tid >> 5, sl = lane & 31, c0 = sl * 4;
    int beg = row_ptr[n], end = row_ptr[n + 1];
    int deg = end - beg;
    __shared__ int s_src[CHUNK];
    __shared__ float s_acc[2][DD];
    const ushort* Hp = (const ushort*)Hin + c0;

    float acc[4] = {0.f, 0.f, 0.f, 0.f};
    for (int cbase = 0; cbase < deg; cbase += CHUNK) {
        int cn = min(CHUNK, deg - cbase);
        __syncthreads();
        for (int i = tid; i < cn; i += 128)
            s_src[i] = col[beg + cbase + i] & 0x7fffffff;
        __syncthreads();
        int i = hw;
        for (; i + 12 < cn; i += 16) {
            int a0 = s_src[i], a1 = s_src[i + 4], a2 = s_src[i + 8], a3 = s_src[i + 12];
            uint2 h0 = *(const uint2*)(Hp + (size_t)a0 * DD);
            uint2 h1 = *(const uint2*)(Hp + (size_t)a1 * DD);
            uint2 h2 = *(const uint2*)(Hp + (size_t)a2 * DD);
            uint2 h3 = *(const uint2*)(Hp + (size_t)a3 * DD);
            acc[0] += bflo(h0.x) + bflo(h1.x) + bflo(h2.x) + bflo(h3.x);
            acc[1] += bfhi(h0.x) + bfhi(h1.x) + bfhi(h2.x) + bfhi(h3.x);
            acc[2] += bflo(h0.y) + bflo(h1.y) + bflo(h2.y) + bflo(h3.y);
            acc[3] += bfhi(h0.y) + bfhi(h1.y) + bfhi(h2.y) + bfhi(h3.y);
        }
        for (; i < cn; i += 4) {
            uint2 hv = *(const uint2*)(Hp + (size_t)s_src[i] * DD);
            acc[0] += bflo(hv.x); acc[1] += bfhi(hv.x);
            acc[2] += bflo(hv.y); acc[3] += bfhi(hv.y);
        }
    }
    #pragma unroll
    for (int j = 0; j < 4; ++j) acc[j] += __shfl_xor(acc[j], 32);
    if (lane < 32) *(float4*)&s_acc[wave][c0] = make_float4(acc[0], acc[1], acc[2], acc[3]);
    __syncthreads();
    if (wave == 0 && lane < 32) {
        const double M = (double)NN * DD;
        double mean_d = stats[0] / M;
        double var_d = stats[1] / M - mean_d * mean_d;
        float mean2 = (float)mean_d;
        float inv2 = rsqrtf((float)var_d + EPSL);
        uint2 selfv = *(const uint2*)(Hp + (size_t)n * DD);  // appended self-loop row
        float sv[4] = {bflo(selfv.x), bfhi(selfv.x), bflo(selfv.y), bfhi(selfv.y)};
        int cnt = deg - 1;
        float rc = 1.f / (float)((cnt > 0) ? cnt : 1);
        float4 xr = *(const float4*)&X[(size_t)n * DD + c0];
        float4 o;
        float a0 = s_acc[0][c0 + 0] + s_acc[1][c0 + 0] - sv[0];
        float a1 = s_acc[0][c0 + 1] + s_acc[1][c0 + 1] - sv[1];
        float a2 = s_acc[0][c0 + 2] + s_acc[1][c0 + 2] - sv[2];
        float a3 = s_acc[0][c0 + 3] + s_acc[1][c0 + 3] - sv[3];
        if (cnt > 0) {
            float4 lw = *(const float4*)&lnw[c0];
            float4 lb = *(const float4*)&lnb[c0];
            o.x = (a0 * rc - mean2) * inv2 * lw.x + lb.x;
            o.y = (a1 * rc - mean2) * inv2 * lw.y + lb.y;
            o.z = (a2 * rc - mean2) * inv2 * lw.z + lb.z;
            o.w = (a3 * rc - mean2) * inv2 * lw.w + lb.w;
        } else {
            o.x = o.y = o.z = o.w = 0.f;   // ref: agg=0, cnt clamped -> 0
        }
        o.x = fmaxf(o.x + xr.x, 0.f);
        o.y = fmaxf(o.y + xr.y, 0.f);
        o.z = fmaxf(o.z + xr.z, 0.f);
        o.w = fmaxf(o.w + xr.w, 0.f);
        *(float4*)&Out[(size_t)n * DD + c0] = o;
    }
}

extern "C" void kernel_launch(void* const* d_in, const int* in_sizes, int n_in,
                              void* d_out, int out_size, void* d_ws, size_t ws_size,
                              hipStream_t stream) {
    const float* x    = (const float*)d_in[0];
    const int*   ei   = (const int*)d_in[1];
    const float* W1   = (const float*)d_in[2];
    const float* as1  = (const float*)d_in[3];
    const float* ad1  = (const float*)d_in[4];
    const float* b1   = (const float*)d_in[5];
    const float* ln1w = (const float*)d_in[6];
    const float* ln1b = (const float*)d_in[7];
    const float* W2   = (const float*)d_in[8];
    const float* as2  = (const float*)d_in[9];
    const float* ad2  = (const float*)d_in[10];
    const float* b2   = (const float*)d_in[11];
    const float* ln2w = (const float*)d_in[12];
    const float* ln2b = (const float*)d_in[13];
    float* out = (float*)d_out;

    char* p = (char*)d_ws;
    auto alloc = [&](size_t bytes) {
        void* r = (void*)p;
        p += (bytes + 255) & ~(size_t)255;
        return r;
    };
    int*    deg     = (int*)alloc((size_t)NN * 4);
    int*    row_ptr = (int*)alloc((size_t)(NN + 1) * 4);
    int*    cursor  = (int*)alloc((size_t)NN * 4);
    double* stats1  = (double*)alloc(16);
    double* stats2  = (double*)alloc(16);
    float2* pstats  = (float2*)alloc((size_t)NN * 8);
    int*    col     = (int*)alloc((size_t)EP * 4);
    bf16*   bufH    = (bf16*)alloc((size_t)NN * DD * 2);   // h1, later h2 (bf16, gathered)
    float*  bufF    = (float*)alloc((size_t)NN * DD * 4);  // out1 (fp32); later out2 (bf16 alias)
    bf16*   out2    = (bf16*)bufF;                         // alias: out1 dead before out2 written
    float*  aS1     = (float*)alloc((size_t)NN * 2 * 4);
    float*  aD1     = (float*)alloc((size_t)NN * 2 * 4);
    float*  aS2     = (float*)alloc((size_t)NN * 4);
    float*  aD2     = (float*)alloc((size_t)NN * 4);

    hipMemsetAsync(deg, 0, (size_t)NN * 4, stream);

    hist_kernel<<<(EP + 255) / 256, 256, 0, stream>>>(ei, deg);
    scan_kernel<<<1, 1024, 0, stream>>>(deg, row_ptr, cursor);
    scatter_kernel<<<(EP + 255) / 256, 256, 0, stream>>>(ei, cursor, col);

    // layer 1: GATConv(128 -> 64, heads=2, concat); LN1+relu deferred into next gemm
    gemm_attn<2, false><<<NN / 16, 128, 0, stream>>>(x, W1, as1, ad1,
                                                     nullptr, nullptr, nullptr,
                                                     bufH, aS1, aD1);
    gat_agg<2, float><<<NN, 128, 0, stream>>>(row_ptr, col, bufH, aS1, aD1, b1, bufF, pstats);
    reduce_stats_kernel<<<1, 1024, 0, stream>>>(pstats, stats1);

    // layer 2: GATConv(128 -> 128, heads=1), input = relu(ln1(out1)) fused into gemm
    gemm_attn<1, true><<<NN / 16, 128, 0, stream>>>(bufF, W2, as2, ad2,
                                                    stats1, ln1w, ln1b,
                                                    bufH, aS2, aD2);
    gat_agg<1, bf16><<<NN, 128, 0, stream>>>(row_ptr, col, bufH, aS2, aD2, b2, out2, pstats);
    reduce_stats_kernel<<<1, 1024, 0, stream>>>(pstats, stats2);

    // SimpleConv mean over original edges + LN2 affine + residual + relu (fused)
    simpleconv_kernel<<<NN, 128, 0, stream>>>(row_ptr, col, out2, x,
                                              stats2, ln2w, ln2b, out);
}

// Round 7
// 416.670 us; speedup vs baseline: 1.1443x; 1.1443x over previous
//
#include <hip/hip_runtime.h>
#include <hip/hip_bf16.h>
#include <cstdint>
#include <cstddef>

#define NN 50000
#define EE 800000
#define DD 128
#define NEG 0.2f
#define EPSL 1e-5f
#define CHUNK 512

// radix/bucket sort config
#define NB   392                 // pass-1 blocks, 2048 edges each (392*2048 >= EE), mult of 4
#define NBKT 196                 // buckets = dst>>8 (dst < 50000 -> 0..195)
#define HM   (NBKT * NB)         // hist matrix size (76832, mult of 4)

typedef __hip_bfloat16 bf16;

__device__ inline float wave_reduce_sum(float v) {
    for (int off = 32; off; off >>= 1) v += __shfl_xor(v, off);
    return v;
}
__device__ inline float bflo(unsigned u) { return __uint_as_float(u << 16); }
__device__ inline float bfhi(unsigned u) { return __uint_as_float(u & 0xffff0000u); }

__device__ inline void store4(float* Out, size_t idx, float4 v) {
    *(float4*)&Out[idx] = v;
}
__device__ inline void store4(bf16* Out, size_t idx, float4 v) {
    union { bf16 b[4]; ushort4 u; } cv;
    cv.b[0] = (bf16)v.x; cv.b[1] = (bf16)v.y; cv.b[2] = (bf16)v.z; cv.b[3] = (bf16)v.w;
    *(ushort4*)&Out[idx] = cv.u;
}

// ================= CSR build: MSD bucket sort (dense writes, no global atomics) ============

// pass A: pack keys + per-block bucket histogram
__global__ __launch_bounds__(256) void pack_hist_kernel(const int* __restrict__ ei,
                                                        unsigned* __restrict__ keys,
                                                        int* __restrict__ histG) {
    __shared__ int lh[NBKT];
    int tid = threadIdx.x;
    for (int t = tid; t < NBKT; t += 256) lh[t] = 0;
    __syncthreads();
    int base = blockIdx.x * 2048;
    #pragma unroll
    for (int j = 0; j < 8; ++j) {
        int i = base + j * 256 + tid;
        if (i < EE) {
            unsigned s = (unsigned)ei[i];
            unsigned d = (unsigned)ei[EE + i];
            keys[i] = (d << 16) | s;
            atomicAdd(&lh[d >> 8], 1);
        }
    }
    __syncthreads();
    for (int t = tid; t < NBKT; t += 256) histG[t * NB + blockIdx.x] = lh[t];
}

// exclusive scan of the (digit-major) hist matrix -> per-(bucket,block) offsets + bucket starts
__global__ __launch_bounds__(1024) void scan_hist_kernel(const int* __restrict__ histG,
                                                         int* __restrict__ offs,
                                                         int* __restrict__ bstart) {
    __shared__ int wsum[16];
    __shared__ int carry_s;
    int tid = threadIdx.x, lane = tid & 63, wv = tid >> 6;
    if (tid == 0) carry_s = 0;
    __syncthreads();
    for (int base = 0; base < HM; base += 4096) {
        int i4 = base + tid * 4;
        int4 v = make_int4(0, 0, 0, 0);
        if (i4 + 3 < HM) v = *(const int4*)&histG[i4];
        else {
            if (i4 + 0 < HM) v.x = histG[i4 + 0];
            if (i4 + 1 < HM) v.y = histG[i4 + 1];
            if (i4 + 2 < HM) v.z = histG[i4 + 2];
            if (i4 + 3 < HM) v.w = histG[i4 + 3];
        }
        int tsum = v.x + v.y + v.z + v.w;
        int x = tsum;
        for (int off = 1; off < 64; off <<= 1) {
            int t = __shfl_up(x, off);
            if (lane >= off) x += t;
        }
        if (lane == 63) wsum[wv] = x;
        __syncthreads();
        if (wv == 0) {
            int s = (lane < 16) ? wsum[lane] : 0;
            for (int off = 1; off < 16; off <<= 1) {
                int t = __shfl_up(s, off);
                if (lane >= off) s += t;
            }
            if (lane < 16) wsum[lane] = s;
        }
        __syncthreads();
        int waveoff = (wv == 0) ? 0 : wsum[wv - 1];
        int carry = carry_s;
        int o0 = carry + waveoff + x - tsum;
        int o1 = o0 + v.x, o2 = o1 + v.y, o3 = o2 + v.z;
        if (i4 + 3 < HM) *(int4*)&offs[i4] = make_int4(o0, o1, o2, o3);
        else {
            if (i4 + 0 < HM) offs[i4 + 0] = o0;
            if (i4 + 1 < HM) offs[i4 + 1] = o1;
            if (i4 + 2 < HM) offs[i4 + 2] = o2;
            if (i4 + 3 < HM) offs[i4 + 3] = o3;
        }
        if (i4 < HM && (i4 % NB) == 0) bstart[i4 / NB] = o0;  // NB mult of 4 => boundary at .x
        __syncthreads();
        if (tid == 0) carry_s += wsum[15];
        __syncthreads();
    }
    if (tid == 0) bstart[NBKT] = carry_s;   // == EE
}

// pass 1 scatter: into per-(bucket,block) contiguous regions (LDS-atomic rank)
__global__ __launch_bounds__(256) void scatter_pass1_kernel(const unsigned* __restrict__ keys,
                                                            const int* __restrict__ offs,
                                                            unsigned* __restrict__ tmp) {
    __shared__ int lofs[NBKT];
    int tid = threadIdx.x;
    for (int t = tid; t < NBKT; t += 256) lofs[t] = offs[t * NB + blockIdx.x];
    __syncthreads();
    int base = blockIdx.x * 2048;
    #pragma unroll
    for (int j = 0; j < 8; ++j) {
        int i = base + j * 256 + tid;
        if (i < EE) {
            unsigned key = keys[i];
            int pos = atomicAdd(&lofs[key >> 24], 1);
            tmp[pos] = key;
        }
    }
}

// pass 2: one block per bucket; counting sort by dst low byte (single-XCD dense writes)
__global__ __launch_bounds__(256) void bucket_sort_kernel(const unsigned* __restrict__ tmp,
                                                          const int* __restrict__ bstart,
                                                          unsigned* __restrict__ col) {
    __shared__ int cnt[256];
    __shared__ int cpos[256];
    __shared__ int wtot[4];
    int tid = threadIdx.x, lane = tid & 63, wv = tid >> 6;
    int s0 = bstart[blockIdx.x], s1 = bstart[blockIdx.x + 1];
    cnt[tid] = 0;
    __syncthreads();
    for (int i = s0 + tid; i < s1; i += 256)
        atomicAdd(&cnt[(tmp[i] >> 16) & 0xFF], 1);
    __syncthreads();
    int v = cnt[tid];
    int x = v;
    for (int off = 1; off < 64; off <<= 1) {
        int t = __shfl_up(x, off);
        if (lane >= off) x += t;
    }
    if (lane == 63) wtot[wv] = x;
    __syncthreads();
    int add = 0;
    for (int k = 0; k < wv; ++k) add += wtot[k];
    cpos[tid] = s0 + add + x - v;   // exclusive scan + bucket base
    __syncthreads();
    for (int i = s0 + tid; i < s1; i += 256) {
        unsigned key = tmp[i];
        int pos = atomicAdd(&cpos[(key >> 16) & 0xFF], 1);
        col[pos] = key;             // grouped by full dst
    }
}

// row_ptr via boundary detection on the dst-sorted keys
__global__ __launch_bounds__(256) void rowptr_kernel(const unsigned* __restrict__ col,
                                                     int* __restrict__ row_ptr) {
    int i = blockIdx.x * 256 + threadIdx.x;
    if (i >= EE) return;
    int d = (int)(col[i] >> 16);
    int dprev = (i == 0) ? -1 : (int)(col[i - 1] >> 16);
    for (int dd = dprev + 1; dd <= d; ++dd) row_ptr[dd] = i;
    if (i == EE - 1) {
        for (int dd = d + 1; dd <= NN; ++dd) row_ptr[dd] = EE;
    }
}

// ---------------- GEMM (+optional fused LN1+relu on input) + attention dots ----------------
template <int H, bool LN>
__global__ __launch_bounds__(128) void gemm_attn(const float* __restrict__ X,
                                                 const float* __restrict__ W,
                                                 const float* __restrict__ att_s,
                                                 const float* __restrict__ att_d,
                                                 const double* __restrict__ stats,
                                                 const float* __restrict__ lnw,
                                                 const float* __restrict__ lnb,
                                                 bf16* __restrict__ Hout,
                                                 float* __restrict__ a_src,
                                                 float* __restrict__ a_dst) {
    const int ROWS = 16;
    int tid = threadIdx.x, lane = tid & 63, wave = tid >> 6;
    __shared__ float xs[ROWS][DD];
    __shared__ float ps_s[ROWS][2], ps_d[ROWS][2];
    int row0 = blockIdx.x * ROWS;

    float mean = 0.f, inv = 1.f, wc = 1.f, bc = 0.f;
    if (LN) {
        const double M = (double)NN * DD;
        double mean_d = stats[0] / M;
        double var_d = stats[1] / M - mean_d * mean_d;
        mean = (float)mean_d;
        inv = rsqrtf((float)var_d + EPSL);
        wc = lnw[tid]; bc = lnb[tid];
    }
    #pragma unroll
    for (int r = 0; r < ROWS; ++r) {
        float v = X[(size_t)(row0 + r) * DD + tid];
        if (LN) v = fmaxf((v - mean) * inv * wc + bc, 0.f);
        xs[r][tid] = v;
    }
    __syncthreads();
    float acc[ROWS] = {0.f};
    for (int k4 = 0; k4 < DD / 4; ++k4) {
        float w0 = W[(size_t)(4 * k4 + 0) * DD + tid];
        float w1 = W[(size_t)(4 * k4 + 1) * DD + tid];
        float w2 = W[(size_t)(4 * k4 + 2) * DD + tid];
        float w3 = W[(size_t)(4 * k4 + 3) * DD + tid];
        #pragma unroll
        for (int r = 0; r < ROWS; ++r) {
            float4 xv = *(const float4*)&xs[r][k4 * 4];
            acc[r] = fmaf(xv.x, w0, acc[r]);
            acc[r] = fmaf(xv.y, w1, acc[r]);
            acc[r] = fmaf(xv.z, w2, acc[r]);
            acc[r] = fmaf(xv.w, w3, acc[r]);
        }
    }
    float as = att_s[tid], ad = att_d[tid];
    #pragma unroll
    for (int r = 0; r < ROWS; ++r) {
        Hout[(size_t)(row0 + r) * DD + tid] = (bf16)acc[r];
        float psum = wave_reduce_sum(acc[r] * as);
        float pdum = wave_reduce_sum(acc[r] * ad);
        if (lane == 0) { ps_s[r][wave] = psum; ps_d[r][wave] = pdum; }
    }
    __syncthreads();
    if (tid < ROWS) {
        int row = row0 + tid;
        if (H == 2) {
            a_src[row * 2 + 0] = ps_s[tid][0];
            a_src[row * 2 + 1] = ps_s[tid][1];
            a_dst[row * 2 + 0] = ps_d[tid][0];
            a_dst[row * 2 + 1] = ps_d[tid][1];
        } else {
            a_src[row] = ps_s[tid][0] + ps_s[tid][1];
            a_dst[row] = ps_d[tid][0] + ps_d[tid][1];
        }
    }
}

// ---------------- fused GAT softmax + aggregate (+per-block LN partials) ------------------
// Implicit self-loop (col holds ORIGINAL edges only): w_self = exp(leaky(aS[n]+aD[n])),
// feature = own row (coalesced). No max-subtraction (scores bounded; softmax shift-invariant).
template <int H, typename OT>
__global__ __launch_bounds__(128) void gat_agg(const int* __restrict__ row_ptr,
                                               const unsigned* __restrict__ col,
                                               const bf16* __restrict__ Hin,
                                               const float* __restrict__ a_src,
                                               const float* __restrict__ a_dst,
                                               const float* __restrict__ bias,
                                               OT* __restrict__ Out,
                                               float2* __restrict__ pstats) {
    int n = blockIdx.x;
    int tid = threadIdx.x, lane = tid & 63, wave = tid >> 6;
    int hw = tid >> 5;            // half-wave 0..3
    int sl = lane & 31;           // sub-lane in half-wave
    int c0 = sl * 4;              // 4 channels per lane
    const int head4 = (H == 2) ? (sl >> 4) : 0;

    int beg = row_ptr[n], end = row_ptr[n + 1];
    int deg = end - beg;

    __shared__ int   s_src[CHUNK];
    __shared__ float s_w[H][CHUNK];
    __shared__ float s_red[8];
    __shared__ float s_acc[2][DD];

    float ad0 = a_dst[n * H + 0];
    float ad1 = (H == 2) ? a_dst[n * H + 1] : 0.f;

    const ushort* Hp = (const ushort*)Hin + c0;

    float dloc0 = 0.f, dloc1 = 0.f;
    float acc[4] = {0.f, 0.f, 0.f, 0.f};

    for (int cbase = 0; cbase < deg; cbase += CHUNK) {
        int cn = min(CHUNK, deg - cbase);
        __syncthreads();
        for (int i = tid; i < cn; i += 128) {
            int s = (int)(col[beg + cbase + i] & 0xffffu);
            s_src[i] = s;
            if (H == 2) {
                float2 av = *(const float2*)&a_src[s * 2];
                float e0 = av.x + ad0; e0 = (e0 > 0.f) ? e0 : NEG * e0;
                float e1 = av.y + ad1; e1 = (e1 > 0.f) ? e1 : NEG * e1;
                float w0 = __expf(e0), w1 = __expf(e1);
                s_w[0][i] = w0; s_w[1][i] = w1;
                dloc0 += w0; dloc1 += w1;
            } else {
                float e0 = a_src[s] + ad0; e0 = (e0 > 0.f) ? e0 : NEG * e0;
                float w0 = __expf(e0);
                s_w[0][i] = w0;
                dloc0 += w0;
            }
        }
        __syncthreads();
        const float* wrow = s_w[head4];
        int i = hw;
        for (; i + 12 < cn; i += 16) {
            int a0 = s_src[i], a1 = s_src[i + 4], a2 = s_src[i + 8], a3 = s_src[i + 12];
            float w0 = wrow[i], w1 = wrow[i + 4], w2 = wrow[i + 8], w3 = wrow[i + 12];
            uint2 h0 = *(const uint2*)(Hp + (size_t)a0 * DD);
            uint2 h1 = *(const uint2*)(Hp + (size_t)a1 * DD);
            uint2 h2 = *(const uint2*)(Hp + (size_t)a2 * DD);
            uint2 h3 = *(const uint2*)(Hp + (size_t)a3 * DD);
            acc[0] = fmaf(w0, bflo(h0.x), acc[0]); acc[1] = fmaf(w0, bfhi(h0.x), acc[1]);
            acc[2] = fmaf(w0, bflo(h0.y), acc[2]); acc[3] = fmaf(w0, bfhi(h0.y), acc[3]);
            acc[0] = fmaf(w1, bflo(h1.x), acc[0]); acc[1] = fmaf(w1, bfhi(h1.x), acc[1]);
            acc[2] = fmaf(w1, bflo(h1.y), acc[2]); acc[3] = fmaf(w1, bfhi(h1.y), acc[3]);
            acc[0] = fmaf(w2, bflo(h2.x), acc[0]); acc[1] = fmaf(w2, bfhi(h2.x), acc[1]);
            acc[2] = fmaf(w2, bflo(h2.y), acc[2]); acc[3] = fmaf(w2, bfhi(h2.y), acc[3]);
            acc[0] = fmaf(w3, bflo(h3.x), acc[0]); acc[1] = fmaf(w3, bfhi(h3.x), acc[1]);
            acc[2] = fmaf(w3, bflo(h3.y), acc[2]); acc[3] = fmaf(w3, bfhi(h3.y), acc[3]);
        }
        for (; i < cn; i += 4) {
            int s = s_src[i];
            float w = wrow[i];
            uint2 hv = *(const uint2*)(Hp + (size_t)s * DD);
            acc[0] = fmaf(w, bflo(hv.x), acc[0]); acc[1] = fmaf(w, bfhi(hv.x), acc[1]);
            acc[2] = fmaf(w, bflo(hv.y), acc[2]); acc[3] = fmaf(w, bfhi(hv.y), acc[3]);
        }
    }

    #pragma unroll
    for (int j = 0; j < 4; ++j) acc[j] += __shfl_xor(acc[j], 32);
    if (lane < 32) *(float4*)&s_acc[wave][c0] = make_float4(acc[0], acc[1], acc[2], acc[3]);

    float d0 = wave_reduce_sum(dloc0);
    float d1 = (H == 2) ? wave_reduce_sum(dloc1) : 0.f;
    if (lane == 0) { s_red[wave] = d0; if (H == 2) s_red[2 + wave] = d1; }
    __syncthreads();

    if (wave == 0 && lane < 32) {
        // implicit self-loop weight per head
        float e0 = a_src[n * H + 0] + ad0; e0 = (e0 > 0.f) ? e0 : NEG * e0;
        float ws0 = __expf(e0);
        float ws1 = 0.f;
        if (H == 2) {
            float e1 = a_src[n * H + 1] + ad1; e1 = (e1 > 0.f) ? e1 : NEG * e1;
            ws1 = __expf(e1);
        }
        float den = (H == 2 && head4 == 1) ? (s_red[2] + s_red[3] + ws1)
                                           : (s_red[0] + s_red[1] + ws0);
        float wself = (H == 2 && head4 == 1) ? ws1 : ws0;
        float rinv = 1.f / (den + 1e-16f);
        uint2 hs = *(const uint2*)(Hp + (size_t)n * DD);   // own row, coalesced
        float4 bi = *(const float4*)&bias[c0];
        float4 o;
        o.x = (s_acc[0][c0 + 0] + s_acc[1][c0 + 0] + wself * bflo(hs.x)) * rinv + bi.x;
        o.y = (s_acc[0][c0 + 1] + s_acc[1][c0 + 1] + wself * bfhi(hs.x)) * rinv + bi.y;
        o.z = (s_acc[0][c0 + 2] + s_acc[1][c0 + 2] + wself * bflo(hs.y)) * rinv + bi.z;
        o.w = (s_acc[0][c0 + 3] + s_acc[1][c0 + 3] + wself * bfhi(hs.y)) * rinv + bi.w;
        store4(Out, (size_t)n * DD + c0, o);
        float t1 = o.x + o.y + o.z + o.w;
        float t2 = o.x * o.x + o.y * o.y + o.z * o.z + o.w * o.w;
        for (int off = 16; off; off >>= 1) {
            t1 += __shfl_xor(t1, off);
            t2 += __shfl_xor(t2, off);
        }
        if (lane == 0) pstats[n] = make_float2(t1, t2);
    }
}

// ---------------- deterministic single-block reduce of per-node LN partials ----------------
__global__ __launch_bounds__(1024) void reduce_stats_kernel(const float2* __restrict__ pstats,
                                                            double* __restrict__ stats) {
    int tid = threadIdx.x, lane = tid & 63, wv = tid >> 6;
    double s1 = 0.0, s2 = 0.0;
    for (int i = tid; i < NN; i += 1024) {
        float2 v = pstats[i];
        s1 += (double)v.x; s2 += (double)v.y;
    }
    for (int off = 32; off; off >>= 1) {
        s1 += __shfl_xor(s1, off);
        s2 += __shfl_xor(s2, off);
    }
    __shared__ double w1[16], w2[16];
    if (lane == 0) { w1[wv] = s1; w2[wv] = s2; }
    __syncthreads();
    if (tid == 0) {
        double a = 0.0, b = 0.0;
        for (int i = 0; i < 16; ++i) { a += w1[i]; b += w2[i]; }
        stats[0] = a; stats[1] = b;
    }
}

// ---------------- SimpleConv(mean, ORIGINAL edges) + fused LN2 affine + residual + relu ----
__global__ __launch_bounds__(128) void simpleconv_kernel(const int* __restrict__ row_ptr,
                                                         const unsigned* __restrict__ col,
                                                         const bf16* __restrict__ Hin,
                                                         const float* __restrict__ X,
                                                         const double* __restrict__ stats,
                                                         const float* __restrict__ lnw,
                                                         const float* __restrict__ lnb,
                                                         float* __restrict__ Out) {
    int n = blockIdx.x;
    int tid = threadIdx.x, lane = tid & 63, wave = tid >> 6;
    int hw = tid >> 5, sl = lane & 31, c0 = sl * 4;
    int beg = row_ptr[n], end = row_ptr[n + 1];
    int deg = end - beg;
    __shared__ int s_src[CHUNK];
    __shared__ float s_acc[2][DD];
    const ushort* Hp = (const ushort*)Hin + c0;

    float acc[4] = {0.f, 0.f, 0.f, 0.f};
    for (int cbase = 0; cbase < deg; cbase += CHUNK) {
        int cn = min(CHUNK, deg - cbase);
        __syncthreads();
        for (int i = tid; i < cn; i += 128)
            s_src[i] = (int)(col[beg + cbase + i] & 0xffffu);
        __syncthreads();
        int i = hw;
        for (; i + 12 < cn; i += 16) {
            int a0 = s_src[i], a1 = s_src[i + 4], a2 = s_src[i + 8], a3 = s_src[i + 12];
            uint2 h0 = *(const uint2*)(Hp + (size_t)a0 * DD);
            uint2 h1 = *(const uint2*)(Hp + (size_t)a1 * DD);
            uint2 h2 = *(const uint2*)(Hp + (size_t)a2 * DD);
            uint2 h3 = *(const uint2*)(Hp + (size_t)a3 * DD);
            acc[0] += bflo(h0.x) + bflo(h1.x) + bflo(h2.x) + bflo(h3.x);
            acc[1] += bfhi(h0.x) + bfhi(h1.x) + bfhi(h2.x) + bfhi(h3.x);
            acc[2] += bflo(h0.y) + bflo(h1.y) + bflo(h2.y) + bflo(h3.y);
            acc[3] += bfhi(h0.y) + bfhi(h1.y) + bfhi(h2.y) + bfhi(h3.y);
        }
        for (; i < cn; i += 4) {
            uint2 hv = *(const uint2*)(Hp + (size_t)s_src[i] * DD);
            acc[0] += bflo(hv.x); acc[1] += bfhi(hv.x);
            acc[2] += bflo(hv.y); acc[3] += bfhi(hv.y);
        }
    }
    #pragma unroll
    for (int j = 0; j < 4; ++j) acc[j] += __shfl_xor(acc[j], 32);
    if (lane < 32) *(float4*)&s_acc[wave][c0] = make_float4(acc[0], acc[1], acc[2], acc[3]);
    __syncthreads();
    if (wave == 0 && lane < 32) {
        const double M = (double)NN * DD;
        double mean_d = stats[0] / M;
        double var_d = stats[1] / M - mean_d * mean_d;
        float mean2 = (float)mean_d;
        float inv2 = rsqrtf((float)var_d + EPSL);
        float rc = 1.f / (float)((deg > 0) ? deg : 1);
        float4 xr = *(const float4*)&X[(size_t)n * DD + c0];
        float4 o;
        float a0 = s_acc[0][c0 + 0] + s_acc[1][c0 + 0];
        float a1 = s_acc[0][c0 + 1] + s_acc[1][c0 + 1];
        float a2 = s_acc[0][c0 + 2] + s_acc[1][c0 + 2];
        float a3 = s_acc[0][c0 + 3] + s_acc[1][c0 + 3];
        if (deg > 0) {
            float4 lw = *(const float4*)&lnw[c0];
            float4 lb = *(const float4*)&lnb[c0];
            o.x = (a0 * rc - mean2) * inv2 * lw.x + lb.x;
            o.y = (a1 * rc - mean2) * inv2 * lw.y + lb.y;
            o.z = (a2 * rc - mean2) * inv2 * lw.z + lb.z;
            o.w = (a3 * rc - mean2) * inv2 * lw.w + lb.w;
        } else {
            o.x = o.y = o.z = o.w = 0.f;
        }
        o.x = fmaxf(o.x + xr.x, 0.f);
        o.y = fmaxf(o.y + xr.y, 0.f);
        o.z = fmaxf(o.z + xr.z, 0.f);
        o.w = fmaxf(o.w + xr.w, 0.f);
        *(float4*)&Out[(size_t)n * DD + c0] = o;
    }
}

extern "C" void kernel_launch(void* const* d_in, const int* in_sizes, int n_in,
                              void* d_out, int out_size, void* d_ws, size_t ws_size,
                              hipStream_t stream) {
    const float* x    = (const float*)d_in[0];
    const int*   ei   = (const int*)d_in[1];
    const float* W1   = (const float*)d_in[2];
    const float* as1  = (const float*)d_in[3];
    const float* ad1  = (const float*)d_in[4];
    const float* b1   = (const float*)d_in[5];
    const float* ln1w = (const float*)d_in[6];
    const float* ln1b = (const float*)d_in[7];
    const float* W2   = (const float*)d_in[8];
    const float* as2  = (const float*)d_in[9];
    const float* ad2  = (const float*)d_in[10];
    const float* b2   = (const float*)d_in[11];
    const float* ln2w = (const float*)d_in[12];
    const float* ln2b = (const float*)d_in[13];
    float* out = (float*)d_out;

    char* p = (char*)d_ws;
    auto alloc = [&](size_t bytes) {
        void* r = (void*)p;
        p += (bytes + 255) & ~(size_t)255;
        return r;
    };
    unsigned* keys    = (unsigned*)alloc((size_t)EE * 4);
    unsigned* tmp     = (unsigned*)alloc((size_t)EE * 4);
    unsigned* col     = (unsigned*)alloc((size_t)EE * 4);
    int*      histG   = (int*)alloc((size_t)HM * 4);
    int*      offs    = (int*)alloc((size_t)HM * 4);
    int*      bstart  = (int*)alloc((size_t)(NBKT + 1) * 4);
    int*      row_ptr = (int*)alloc((size_t)(NN + 1) * 4);
    double*   stats1  = (double*)alloc(16);
    double*   stats2  = (double*)alloc(16);
    float2*   pstats  = (float2*)alloc((size_t)NN * 8);
    bf16*     bufH    = (bf16*)alloc((size_t)NN * DD * 2);   // h1, later h2 (bf16, gathered)
    float*    bufF    = (float*)alloc((size_t)NN * DD * 4);  // out1 fp32; later out2 bf16 alias
    bf16*     out2    = (bf16*)bufF;
    float*    aS1     = (float*)alloc((size_t)NN * 2 * 4);
    float*    aD1     = (float*)alloc((size_t)NN * 2 * 4);
    float*    aS2     = (float*)alloc((size_t)NN * 4);
    float*    aD2     = (float*)alloc((size_t)NN * 4);

    // ---- CSR build (bucket sort, no global atomics, dense writes) ----
    pack_hist_kernel<<<NB, 256, 0, stream>>>(ei, keys, histG);
    scan_hist_kernel<<<1, 1024, 0, stream>>>(histG, offs, bstart);
    scatter_pass1_kernel<<<NB, 256, 0, stream>>>(keys, offs, tmp);
    bucket_sort_kernel<<<NBKT, 256, 0, stream>>>(tmp, bstart, col);
    rowptr_kernel<<<(EE + 255) / 256, 256, 0, stream>>>(col, row_ptr);

    // layer 1: GATConv(128 -> 64, heads=2, concat); LN1+relu deferred into next gemm
    gemm_attn<2, false><<<NN / 16, 128, 0, stream>>>(x, W1, as1, ad1,
                                                     nullptr, nullptr, nullptr,
                                                     bufH, aS1, aD1);
    gat_agg<2, float><<<NN, 128, 0, stream>>>(row_ptr, col, bufH, aS1, aD1, b1, bufF, pstats);
    reduce_stats_kernel<<<1, 1024, 0, stream>>>(pstats, stats1);

    // layer 2: GATConv(128 -> 128, heads=1), input = relu(ln1(out1)) fused into gemm
    gemm_attn<1, true><<<NN / 16, 128, 0, stream>>>(bufF, W2, as2, ad2,
                                                    stats1, ln1w, ln1b,
                                                    bufH, aS2, aD2);
    gat_agg<1, bf16><<<NN, 128, 0, stream>>>(row_ptr, col, bufH, aS2, aD2, b2, out2, pstats);
    reduce_stats_kernel<<<1, 1024, 0, stream>>>(pstats, stats2);

    // SimpleConv mean over original edges + LN2 affine + residual + relu (fused)
    simpleconv_kernel<<<NN, 128, 0, stream>>>(row_ptr, col, out2, x,
                                              stats2, ln2w, ln2b, out);
}

// Round 8
// 381.327 us; speedup vs baseline: 1.2504x; 1.0927x over previous
//
#include <hip/hip_runtime.h>
#include <hip/hip_bf16.h>
#include <cstdint>
#include <cstddef>

#define NN 50000
#define EE 800000
#define DD 128
#define NEG 0.2f
#define EPSL 1e-5f
#define CHUNK 512

// radix/bucket sort config
#define NB   392                 // pass-1 blocks, 2048 edges each (392*2048 >= EE), mult of 4
#define NBKT 196                 // buckets = dst>>8 (dst < 50000 -> 0..195)
#define HM   (NBKT * NB)         // hist matrix size (76832, mult of 4)

#define GROWS 64                 // rows per gemm block (4 waves x 16)

typedef __hip_bfloat16 bf16;
typedef short short8 __attribute__((ext_vector_type(8)));   // 8 bf16 = 4 VGPRs (guide §3)
typedef float f32x4 __attribute__((ext_vector_type(4)));

__device__ inline float wave_reduce_sum(float v) {
    for (int off = 32; off; off >>= 1) v += __shfl_xor(v, off);
    return v;
}
__device__ inline float bflo(unsigned u) { return __uint_as_float(u << 16); }
__device__ inline float bfhi(unsigned u) { return __uint_as_float(u & 0xffff0000u); }

__device__ inline unsigned short f2bf(float f) {
    __bf16 h = (__bf16)f;
    return __builtin_bit_cast(unsigned short, h);
}

__device__ inline void store4(float* Out, size_t idx, float4 v) {
    *(float4*)&Out[idx] = v;
}
__device__ inline void store4(bf16* Out, size_t idx, float4 v) {
    union { bf16 b[4]; ushort4 u; } cv;
    cv.b[0] = (bf16)v.x; cv.b[1] = (bf16)v.y; cv.b[2] = (bf16)v.z; cv.b[3] = (bf16)v.w;
    *(ushort4*)&Out[idx] = cv.u;
}

// ================= CSR build: MSD bucket sort (dense writes, no global atomics) ============

__global__ __launch_bounds__(256) void pack_hist_kernel(const int* __restrict__ ei,
                                                        unsigned* __restrict__ keys,
                                                        int* __restrict__ histG) {
    __shared__ int lh[NBKT];
    int tid = threadIdx.x;
    for (int t = tid; t < NBKT; t += 256) lh[t] = 0;
    __syncthreads();
    int base = blockIdx.x * 2048;
    #pragma unroll
    for (int j = 0; j < 8; ++j) {
        int i = base + j * 256 + tid;
        if (i < EE) {
            unsigned s = (unsigned)ei[i];
            unsigned d = (unsigned)ei[EE + i];
            keys[i] = (d << 16) | s;
            atomicAdd(&lh[d >> 8], 1);
        }
    }
    __syncthreads();
    for (int t = tid; t < NBKT; t += 256) histG[t * NB + blockIdx.x] = lh[t];
}

__global__ __launch_bounds__(1024) void scan_hist_kernel(const int* __restrict__ histG,
                                                         int* __restrict__ offs,
                                                         int* __restrict__ bstart) {
    __shared__ int wsum[16];
    __shared__ int carry_s;
    int tid = threadIdx.x, lane = tid & 63, wv = tid >> 6;
    if (tid == 0) carry_s = 0;
    __syncthreads();
    for (int base = 0; base < HM; base += 4096) {
        int i4 = base + tid * 4;
        int4 v = make_int4(0, 0, 0, 0);
        if (i4 + 3 < HM) v = *(const int4*)&histG[i4];
        else {
            if (i4 + 0 < HM) v.x = histG[i4 + 0];
            if (i4 + 1 < HM) v.y = histG[i4 + 1];
            if (i4 + 2 < HM) v.z = histG[i4 + 2];
            if (i4 + 3 < HM) v.w = histG[i4 + 3];
        }
        int tsum = v.x + v.y + v.z + v.w;
        int x = tsum;
        for (int off = 1; off < 64; off <<= 1) {
            int t = __shfl_up(x, off);
            if (lane >= off) x += t;
        }
        if (lane == 63) wsum[wv] = x;
        __syncthreads();
        if (wv == 0) {
            int s = (lane < 16) ? wsum[lane] : 0;
            for (int off = 1; off < 16; off <<= 1) {
                int t = __shfl_up(s, off);
                if (lane >= off) s += t;
            }
            if (lane < 16) wsum[lane] = s;
        }
        __syncthreads();
        int waveoff = (wv == 0) ? 0 : wsum[wv - 1];
        int carry = carry_s;
        int o0 = carry + waveoff + x - tsum;
        int o1 = o0 + v.x, o2 = o1 + v.y, o3 = o2 + v.z;
        if (i4 + 3 < HM) *(int4*)&offs[i4] = make_int4(o0, o1, o2, o3);
        else {
            if (i4 + 0 < HM) offs[i4 + 0] = o0;
            if (i4 + 1 < HM) offs[i4 + 1] = o1;
            if (i4 + 2 < HM) offs[i4 + 2] = o2;
            if (i4 + 3 < HM) offs[i4 + 3] = o3;
        }
        if (i4 < HM && (i4 % NB) == 0) bstart[i4 / NB] = o0;
        __syncthreads();
        if (tid == 0) carry_s += wsum[15];
        __syncthreads();
    }
    if (tid == 0) bstart[NBKT] = carry_s;   // == EE
}

__global__ __launch_bounds__(256) void scatter_pass1_kernel(const unsigned* __restrict__ keys,
                                                            const int* __restrict__ offs,
                                                            unsigned* __restrict__ tmp) {
    __shared__ int lofs[NBKT];
    int tid = threadIdx.x;
    for (int t = tid; t < NBKT; t += 256) lofs[t] = offs[t * NB + blockIdx.x];
    __syncthreads();
    int base = blockIdx.x * 2048;
    #pragma unroll
    for (int j = 0; j < 8; ++j) {
        int i = base + j * 256 + tid;
        if (i < EE) {
            unsigned key = keys[i];
            int pos = atomicAdd(&lofs[key >> 24], 1);
            tmp[pos] = key;
        }
    }
}

__global__ __launch_bounds__(256) void bucket_sort_kernel(const unsigned* __restrict__ tmp,
                                                          const int* __restrict__ bstart,
                                                          unsigned* __restrict__ col) {
    __shared__ int cnt[256];
    __shared__ int cpos[256];
    __shared__ int wtot[4];
    int tid = threadIdx.x, lane = tid & 63, wv = tid >> 6;
    int s0 = bstart[blockIdx.x], s1 = bstart[blockIdx.x + 1];
    cnt[tid] = 0;
    __syncthreads();
    for (int i = s0 + tid; i < s1; i += 256)
        atomicAdd(&cnt[(tmp[i] >> 16) & 0xFF], 1);
    __syncthreads();
    int v = cnt[tid];
    int x = v;
    for (int off = 1; off < 64; off <<= 1) {
        int t = __shfl_up(x, off);
        if (lane >= off) x += t;
    }
    if (lane == 63) wtot[wv] = x;
    __syncthreads();
    int add = 0;
    for (int k = 0; k < wv; ++k) add += wtot[k];
    cpos[tid] = s0 + add + x - v;
    __syncthreads();
    for (int i = s0 + tid; i < s1; i += 256) {
        unsigned key = tmp[i];
        int pos = atomicAdd(&cpos[(key >> 16) & 0xFF], 1);
        col[pos] = key;
    }
}

__global__ __launch_bounds__(256) void rowptr_kernel(const unsigned* __restrict__ col,
                                                     int* __restrict__ row_ptr) {
    int i = blockIdx.x * 256 + threadIdx.x;
    if (i >= EE) return;
    int d = (int)(col[i] >> 16);
    int dprev = (i == 0) ? -1 : (int)(col[i - 1] >> 16);
    for (int dd = dprev + 1; dd <= d; ++dd) row_ptr[dd] = i;
    if (i == EE - 1) {
        for (int dd = d + 1; dd <= NN; ++dd) row_ptr[dd] = EE;
    }
}

// ================= MFMA GEMM (+optional fused LN1+relu) + attention dots ===================
// 256 threads = 4 waves, 64 rows/block. W^T staged bf16 in LDS (pad 136), X staged bf16.
// mfma_f32_16x16x32_bf16: A[m=lane&15][k=quad*8+j], B[n=lane&15][k=quad*8+j],
// C/D: col=lane&15, row=quad*4+reg  (HW-verified layouts).
template <int H, bool LN>
__global__ __launch_bounds__(256) void gemm_attn(const float* __restrict__ X,
                                                 const float* __restrict__ W,
                                                 const float* __restrict__ att_s,
                                                 const float* __restrict__ att_d,
                                                 const double* __restrict__ stats,
                                                 const float* __restrict__ lnw,
                                                 const float* __restrict__ lnb,
                                                 bf16* __restrict__ Hout,
                                                 float* __restrict__ a_src,
                                                 float* __restrict__ a_dst) {
    __shared__ __align__(16) char lds[(128 * 136 + 64 * 136) * 2];  // 52224 B
    unsigned short* Bt = (unsigned short*)lds;              // [128][136] n-major (W^T)
    unsigned short* As = (unsigned short*)(lds + 128 * 136 * 2);  // [64][136]
    float* Cs = (float*)lds;                                // [64][132] (reuse, 33792 B)

    int tid = threadIdx.x;
    int c = tid & 127, half = tid >> 7;
    int row0 = blockIdx.x * GROWS;

    float mean = 0.f, inv = 1.f, wc = 1.f, bc = 0.f;
    if (LN) {
        const double M = (double)NN * DD;
        double mean_d = stats[0] / M;
        double var_d = stats[1] / M - mean_d * mean_d;
        mean = (float)mean_d;
        inv = rsqrtf((float)var_d + EPSL);
        wc = lnw[c]; bc = lnb[c];
    }

    // stage W -> Bt transposed (pairs of k per b32 write)
    #pragma unroll 4
    for (int i = 0; i < 32; ++i) {
        int k0 = i * 4 + half * 2;
        float wa = W[(size_t)k0 * DD + c];
        float wb = W[(size_t)(k0 + 1) * DD + c];
        unsigned pk = (unsigned)f2bf(wa) | ((unsigned)f2bf(wb) << 16);
        *(unsigned*)&Bt[c * 136 + k0] = pk;
    }
    // stage X (+LN+relu) -> As
    #pragma unroll 4
    for (int i = 0; i < 32; ++i) {
        int r = i * 2 + half;
        int row = row0 + r;
        float v = (row < NN) ? X[(size_t)row * DD + c] : 0.f;
        if (LN) v = fmaxf((v - mean) * inv * wc + bc, 0.f);
        As[r * 136 + c] = f2bf(v);
    }
    __syncthreads();

    // MFMA phase: wave w computes rows w*16..+16, all 128 cols (8 tiles)
    int lane = tid & 63, w = tid >> 6;
    int l15 = lane & 15, quad = lane >> 4;
    f32x4 acc[8];
    #pragma unroll
    for (int t = 0; t < 8; ++t) acc[t] = 0.f;
    const unsigned short* Arow = As + (w * 16 + l15) * 136 + quad * 8;
    const unsigned short* Brow = Bt + l15 * 136 + quad * 8;
    #pragma unroll
    for (int ks = 0; ks < 4; ++ks) {
        short8 a = *(const short8*)(Arow + ks * 32);
        #pragma unroll
        for (int t = 0; t < 8; ++t) {
            short8 b = *(const short8*)(Brow + t * 16 * 136 + ks * 32);
            acc[t] = __builtin_amdgcn_mfma_f32_16x16x32_bf16(a, b, acc[t], 0, 0, 0);
        }
    }
    __syncthreads();   // all waves done reading Bt/As; Cs may overwrite

    // write C tile to LDS for coalesced readout
    #pragma unroll
    for (int t = 0; t < 8; ++t)
        #pragma unroll
        for (int r = 0; r < 4; ++r)
            Cs[(w * 16 + quad * 4 + r) * 132 + t * 16 + l15] = acc[t][r];

    // attention dots straight from accumulators (col = t*16+l15, head = t>>2 for H=2)
    float ds0[4] = {0.f, 0.f, 0.f, 0.f}, dd0[4] = {0.f, 0.f, 0.f, 0.f};
    float ds1[4] = {0.f, 0.f, 0.f, 0.f}, dd1[4] = {0.f, 0.f, 0.f, 0.f};
    #pragma unroll
    for (int t = 0; t < 8; ++t) {
        float as = att_s[t * 16 + l15];
        float ad = att_d[t * 16 + l15];
        if (H == 2 && t >= 4) {
            #pragma unroll
            for (int r = 0; r < 4; ++r) {
                ds1[r] = fmaf(acc[t][r], as, ds1[r]);
                dd1[r] = fmaf(acc[t][r], ad, dd1[r]);
            }
        } else {
            #pragma unroll
            for (int r = 0; r < 4; ++r) {
                ds0[r] = fmaf(acc[t][r], as, ds0[r]);
                dd0[r] = fmaf(acc[t][r], ad, dd0[r]);
            }
        }
    }
    #pragma unroll
    for (int off = 1; off < 16; off <<= 1) {
        #pragma unroll
        for (int r = 0; r < 4; ++r) {
            ds0[r] += __shfl_xor(ds0[r], off);
            dd0[r] += __shfl_xor(dd0[r], off);
            if (H == 2) { ds1[r] += __shfl_xor(ds1[r], off); dd1[r] += __shfl_xor(dd1[r], off); }
        }
    }
    if (l15 == 0) {
        #pragma unroll
        for (int r = 0; r < 4; ++r) {
            int row = row0 + w * 16 + quad * 4 + r;
            if (row < NN) {
                if (H == 2) {
                    a_src[row * 2 + 0] = ds0[r];
                    a_src[row * 2 + 1] = ds1[r];
                    a_dst[row * 2 + 0] = dd0[r];
                    a_dst[row * 2 + 1] = dd1[r];
                } else {
                    a_src[row] = ds0[r];
                    a_dst[row] = dd0[r];
                }
            }
        }
    }
    __syncthreads();

    // coalesced bf16 row stores
    unsigned short* Hp = (unsigned short*)Hout;
    #pragma unroll 4
    for (int i = 0; i < 32; ++i) {
        int r = i * 2 + half;
        int row = row0 + r;
        if (row < NN) Hp[(size_t)row * DD + c] = f2bf(Cs[r * 132 + c]);
    }
}

// ---------------- fused GAT softmax + aggregate (+per-block LN partials) ------------------
template <int H, typename OT>
__global__ __launch_bounds__(128) void gat_agg(const int* __restrict__ row_ptr,
                                               const unsigned* __restrict__ col,
                                               const bf16* __restrict__ Hin,
                                               const float* __restrict__ a_src,
                                               const float* __restrict__ a_dst,
                                               const float* __restrict__ bias,
                                               OT* __restrict__ Out,
                                               float2* __restrict__ pstats) {
    int n = blockIdx.x;
    int tid = threadIdx.x, lane = tid & 63, wave = tid >> 6;
    int hw = tid >> 5;
    int sl = lane & 31;
    int c0 = sl * 4;
    const int head4 = (H == 2) ? (sl >> 4) : 0;

    int beg = row_ptr[n], end = row_ptr[n + 1];
    int deg = end - beg;

    __shared__ int   s_src[CHUNK];
    __shared__ float s_w[H][CHUNK];
    __shared__ float s_red[8];
    __shared__ float s_acc[2][DD];

    float ad0 = a_dst[n * H + 0];
    float ad1 = (H == 2) ? a_dst[n * H + 1] : 0.f;

    const ushort* Hp = (const ushort*)Hin + c0;

    float dloc0 = 0.f, dloc1 = 0.f;
    float acc[4] = {0.f, 0.f, 0.f, 0.f};

    for (int cbase = 0; cbase < deg; cbase += CHUNK) {
        int cn = min(CHUNK, deg - cbase);
        __syncthreads();
        for (int i = tid; i < cn; i += 128) {
            int s = (int)(col[beg + cbase + i] & 0xffffu);
            s_src[i] = s;
            if (H == 2) {
                float2 av = *(const float2*)&a_src[s * 2];
                float e0 = av.x + ad0; e0 = (e0 > 0.f) ? e0 : NEG * e0;
                float e1 = av.y + ad1; e1 = (e1 > 0.f) ? e1 : NEG * e1;
                float w0 = __expf(e0), w1 = __expf(e1);
                s_w[0][i] = w0; s_w[1][i] = w1;
                dloc0 += w0; dloc1 += w1;
            } else {
                float e0 = a_src[s] + ad0; e0 = (e0 > 0.f) ? e0 : NEG * e0;
                float w0 = __expf(e0);
                s_w[0][i] = w0;
                dloc0 += w0;
            }
        }
        __syncthreads();
        const float* wrow = s_w[head4];
        int i = hw;
        for (; i + 12 < cn; i += 16) {
            int a0 = s_src[i], a1 = s_src[i + 4], a2 = s_src[i + 8], a3 = s_src[i + 12];
            float w0 = wrow[i], w1 = wrow[i + 4], w2 = wrow[i + 8], w3 = wrow[i + 12];
            uint2 h0 = *(const uint2*)(Hp + (size_t)a0 * DD);
            uint2 h1 = *(const uint2*)(Hp + (size_t)a1 * DD);
            uint2 h2 = *(const uint2*)(Hp + (size_t)a2 * DD);
            uint2 h3 = *(const uint2*)(Hp + (size_t)a3 * DD);
            acc[0] = fmaf(w0, bflo(h0.x), acc[0]); acc[1] = fmaf(w0, bfhi(h0.x), acc[1]);
            acc[2] = fmaf(w0, bflo(h0.y), acc[2]); acc[3] = fmaf(w0, bfhi(h0.y), acc[3]);
            acc[0] = fmaf(w1, bflo(h1.x), acc[0]); acc[1] = fmaf(w1, bfhi(h1.x), acc[1]);
            acc[2] = fmaf(w1, bflo(h1.y), acc[2]); acc[3] = fmaf(w1, bfhi(h1.y), acc[3]);
            acc[0] = fmaf(w2, bflo(h2.x), acc[0]); acc[1] = fmaf(w2, bfhi(h2.x), acc[1]);
            acc[2] = fmaf(w2, bflo(h2.y), acc[2]); acc[3] = fmaf(w2, bfhi(h2.y), acc[3]);
            acc[0] = fmaf(w3, bflo(h3.x), acc[0]); acc[1] = fmaf(w3, bfhi(h3.x), acc[1]);
            acc[2] = fmaf(w3, bflo(h3.y), acc[2]); acc[3] = fmaf(w3, bfhi(h3.y), acc[3]);
        }
        for (; i < cn; i += 4) {
            int s = s_src[i];
            float w = wrow[i];
            uint2 hv = *(const uint2*)(Hp + (size_t)s * DD);
            acc[0] = fmaf(w, bflo(hv.x), acc[0]); acc[1] = fmaf(w, bfhi(hv.x), acc[1]);
            acc[2] = fmaf(w, bflo(hv.y), acc[2]); acc[3] = fmaf(w, bfhi(hv.y), acc[3]);
        }
    }

    #pragma unroll
    for (int j = 0; j < 4; ++j) acc[j] += __shfl_xor(acc[j], 32);
    if (lane < 32) *(float4*)&s_acc[wave][c0] = make_float4(acc[0], acc[1], acc[2], acc[3]);

    float d0 = wave_reduce_sum(dloc0);
    float d1 = (H == 2) ? wave_reduce_sum(dloc1) : 0.f;
    if (lane == 0) { s_red[wave] = d0; if (H == 2) s_red[2 + wave] = d1; }
    __syncthreads();

    if (wave == 0 && lane < 32) {
        float e0 = a_src[n * H + 0] + ad0; e0 = (e0 > 0.f) ? e0 : NEG * e0;
        float ws0 = __expf(e0);
        float ws1 = 0.f;
        if (H == 2) {
            float e1 = a_src[n * H + 1] + ad1; e1 = (e1 > 0.f) ? e1 : NEG * e1;
            ws1 = __expf(e1);
        }
        float den = (H == 2 && head4 == 1) ? (s_red[2] + s_red[3] + ws1)
                                           : (s_red[0] + s_red[1] + ws0);
        float wself = (H == 2 && head4 == 1) ? ws1 : ws0;
        float rinv = 1.f / (den + 1e-16f);
        uint2 hs = *(const uint2*)(Hp + (size_t)n * DD);
        float4 bi = *(const float4*)&bias[c0];
        float4 o;
        o.x = (s_acc[0][c0 + 0] + s_acc[1][c0 + 0] + wself * bflo(hs.x)) * rinv + bi.x;
        o.y = (s_acc[0][c0 + 1] + s_acc[1][c0 + 1] + wself * bfhi(hs.x)) * rinv + bi.y;
        o.z = (s_acc[0][c0 + 2] + s_acc[1][c0 + 2] + wself * bflo(hs.y)) * rinv + bi.z;
        o.w = (s_acc[0][c0 + 3] + s_acc[1][c0 + 3] + wself * bfhi(hs.y)) * rinv + bi.w;
        store4(Out, (size_t)n * DD + c0, o);
        float t1 = o.x + o.y + o.z + o.w;
        float t2 = o.x * o.x + o.y * o.y + o.z * o.z + o.w * o.w;
        for (int off = 16; off; off >>= 1) {
            t1 += __shfl_xor(t1, off);
            t2 += __shfl_xor(t2, off);
        }
        if (lane == 0) pstats[n] = make_float2(t1, t2);
    }
}

// ---------------- deterministic single-block reduce of per-node LN partials ----------------
__global__ __launch_bounds__(1024) void reduce_stats_kernel(const float2* __restrict__ pstats,
                                                            double* __restrict__ stats) {
    int tid = threadIdx.x, lane = tid & 63, wv = tid >> 6;
    double s1 = 0.0, s2 = 0.0;
    for (int i = tid; i < NN; i += 1024) {
        float2 v = pstats[i];
        s1 += (double)v.x; s2 += (double)v.y;
    }
    for (int off = 32; off; off >>= 1) {
        s1 += __shfl_xor(s1, off);
        s2 += __shfl_xor(s2, off);
    }
    __shared__ double w1[16], w2[16];
    if (lane == 0) { w1[wv] = s1; w2[wv] = s2; }
    __syncthreads();
    if (tid == 0) {
        double a = 0.0, b = 0.0;
        for (int i = 0; i < 16; ++i) { a += w1[i]; b += w2[i]; }
        stats[0] = a; stats[1] = b;
    }
}

// ---------------- SimpleConv(mean, ORIGINAL edges) + fused LN2 affine + residual + relu ----
__global__ __launch_bounds__(128) void simpleconv_kernel(const int* __restrict__ row_ptr,
                                                         const unsigned* __restrict__ col,
                                                         const bf16* __restrict__ Hin,
                                                         const float* __restrict__ X,
                                                         const double* __restrict__ stats,
                                                         const float* __restrict__ lnw,
                                                         const float* __restrict__ lnb,
                                                         float* __restrict__ Out) {
    int n = blockIdx.x;
    int tid = threadIdx.x, lane = tid & 63, wave = tid >> 6;
    int hw = tid >> 5, sl = lane & 31, c0 = sl * 4;
    int beg = row_ptr[n], end = row_ptr[n + 1];
    int deg = end - beg;
    __shared__ int s_src[CHUNK];
    __shared__ float s_acc[2][DD];
    const ushort* Hp = (const ushort*)Hin + c0;

    float acc[4] = {0.f, 0.f, 0.f, 0.f};
    for (int cbase = 0; cbase < deg; cbase += CHUNK) {
        int cn = min(CHUNK, deg - cbase);
        __syncthreads();
        for (int i = tid; i < cn; i += 128)
            s_src[i] = (int)(col[beg + cbase + i] & 0xffffu);
        __syncthreads();
        int i = hw;
        for (; i + 12 < cn; i += 16) {
            int a0 = s_src[i], a1 = s_src[i + 4], a2 = s_src[i + 8], a3 = s_src[i + 12];
            uint2 h0 = *(const uint2*)(Hp + (size_t)a0 * DD);
            uint2 h1 = *(const uint2*)(Hp + (size_t)a1 * DD);
            uint2 h2 = *(const uint2*)(Hp + (size_t)a2 * DD);
            uint2 h3 = *(const uint2*)(Hp + (size_t)a3 * DD);
            acc[0] += bflo(h0.x) + bflo(h1.x) + bflo(h2.x) + bflo(h3.x);
            acc[1] += bfhi(h0.x) + bfhi(h1.x) + bfhi(h2.x) + bfhi(h3.x);
            acc[2] += bflo(h0.y) + bflo(h1.y) + bflo(h2.y) + bflo(h3.y);
            acc[3] += bfhi(h0.y) + bfhi(h1.y) + bfhi(h2.y) + bfhi(h3.y);
        }
        for (; i < cn; i += 4) {
            uint2 hv = *(const uint2*)(Hp + (size_t)s_src[i] * DD);
            acc[0] += bflo(hv.x); acc[1] += bfhi(hv.x);
            acc[2] += bflo(hv.y); acc[3] += bfhi(hv.y);
        }
    }
    #pragma unroll
    for (int j = 0; j < 4; ++j) acc[j] += __shfl_xor(acc[j], 32);
    if (lane < 32) *(float4*)&s_acc[wave][c0] = make_float4(acc[0], acc[1], acc[2], acc[3]);
    __syncthreads();
    if (wave == 0 && lane < 32) {
        const double M = (double)NN * DD;
        double mean_d = stats[0] / M;
        double var_d = stats[1] / M - mean_d * mean_d;
        float mean2 = (float)mean_d;
        float inv2 = rsqrtf((float)var_d + EPSL);
        float rc = 1.f / (float)((deg > 0) ? deg : 1);
        float4 xr = *(const float4*)&X[(size_t)n * DD + c0];
        float4 o;
        float a0 = s_acc[0][c0 + 0] + s_acc[1][c0 + 0];
        float a1 = s_acc[0][c0 + 1] + s_acc[1][c0 + 1];
        float a2 = s_acc[0][c0 + 2] + s_acc[1][c0 + 2];
        float a3 = s_acc[0][c0 + 3] + s_acc[1][c0 + 3];
        if (deg > 0) {
            float4 lw = *(const float4*)&lnw[c0];
            float4 lb = *(const float4*)&lnb[c0];
            o.x = (a0 * rc - mean2) * inv2 * lw.x + lb.x;
            o.y = (a1 * rc - mean2) * inv2 * lw.y + lb.y;
            o.z = (a2 * rc - mean2) * inv2 * lw.z + lb.z;
            o.w = (a3 * rc - mean2) * inv2 * lw.w + lb.w;
        } else {
            o.x = o.y = o.z = o.w = 0.f;
        }
        o.x = fmaxf(o.x + xr.x, 0.f);
        o.y = fmaxf(o.y + xr.y, 0.f);
        o.z = fmaxf(o.z + xr.z, 0.f);
        o.w = fmaxf(o.w + xr.w, 0.f);
        *(float4*)&Out[(size_t)n * DD + c0] = o;
    }
}

extern "C" void kernel_launch(void* const* d_in, const int* in_sizes, int n_in,
                              void* d_out, int out_size, void* d_ws, size_t ws_size,
                              hipStream_t stream) {
    const float* x    = (const float*)d_in[0];
    const int*   ei   = (const int*)d_in[1];
    const float* W1   = (const float*)d_in[2];
    const float* as1  = (const float*)d_in[3];
    const float* ad1  = (const float*)d_in[4];
    const float* b1   = (const float*)d_in[5];
    const float* ln1w = (const float*)d_in[6];
    const float* ln1b = (const float*)d_in[7];
    const float* W2   = (const float*)d_in[8];
    const float* as2  = (const float*)d_in[9];
    const float* ad2  = (const float*)d_in[10];
    const float* b2   = (const float*)d_in[11];
    const float* ln2w = (const float*)d_in[12];
    const float* ln2b = (const float*)d_in[13];
    float* out = (float*)d_out;

    char* p = (char*)d_ws;
    auto alloc = [&](size_t bytes) {
        void* r = (void*)p;
        p += (bytes + 255) & ~(size_t)255;
        return r;
    };
    unsigned* keys    = (unsigned*)alloc((size_t)EE * 4);
    unsigned* tmp     = (unsigned*)alloc((size_t)EE * 4);
    unsigned* col     = (unsigned*)alloc((size_t)EE * 4);
    int*      histG   = (int*)alloc((size_t)HM * 4);
    int*      offs    = (int*)alloc((size_t)HM * 4);
    int*      bstart  = (int*)alloc((size_t)(NBKT + 1) * 4);
    int*      row_ptr = (int*)alloc((size_t)(NN + 1) * 4);
    double*   stats1  = (double*)alloc(16);
    double*   stats2  = (double*)alloc(16);
    float2*   pstats  = (float2*)alloc((size_t)NN * 8);
    bf16*     bufH    = (bf16*)alloc((size_t)NN * DD * 2);   // h1, later h2 (bf16, gathered)
    float*    bufF    = (float*)alloc((size_t)NN * DD * 4);  // out1 fp32; later out2 bf16 alias
    bf16*     out2    = (bf16*)bufF;
    float*    aS1     = (float*)alloc((size_t)NN * 2 * 4);
    float*    aD1     = (float*)alloc((size_t)NN * 2 * 4);
    float*    aS2     = (float*)alloc((size_t)NN * 4);
    float*    aD2     = (float*)alloc((size_t)NN * 4);

    // ---- CSR build (bucket sort, no global atomics, dense writes) ----
    pack_hist_kernel<<<NB, 256, 0, stream>>>(ei, keys, histG);
    scan_hist_kernel<<<1, 1024, 0, stream>>>(histG, offs, bstart);
    scatter_pass1_kernel<<<NB, 256, 0, stream>>>(keys, offs, tmp);
    bucket_sort_kernel<<<NBKT, 256, 0, stream>>>(tmp, bstart, col);
    rowptr_kernel<<<(EE + 255) / 256, 256, 0, stream>>>(col, row_ptr);

    const int GB = (NN + GROWS - 1) / GROWS;   // 782

    // layer 1: GATConv(128 -> 64, heads=2, concat); LN1+relu deferred into next gemm
    gemm_attn<2, false><<<GB, 256, 0, stream>>>(x, W1, as1, ad1,
                                                nullptr, nullptr, nullptr,
                                                bufH, aS1, aD1);
    gat_agg<2, float><<<NN, 128, 0, stream>>>(row_ptr, col, bufH, aS1, aD1, b1, bufF, pstats);
    reduce_stats_kernel<<<1, 1024, 0, stream>>>(pstats, stats1);

    // layer 2: GATConv(128 -> 128, heads=1), input = relu(ln1(out1)) fused into gemm
    gemm_attn<1, true><<<GB, 256, 0, stream>>>(bufF, W2, as2, ad2,
                                               stats1, ln1w, ln1b,
                                               bufH, aS2, aD2);
    gat_agg<1, bf16><<<NN, 128, 0, stream>>>(row_ptr, col, bufH, aS2, aD2, b2, out2, pstats);
    reduce_stats_kernel<<<1, 1024, 0, stream>>>(pstats, stats2);

    // SimpleConv mean over original edges + LN2 affine + residual + relu (fused)
    simpleconv_kernel<<<NN, 128, 0, stream>>>(row_ptr, col, out2, x,
                                              stats2, ln2w, ln2b, out);
}

// Round 9
// 338.796 us; speedup vs baseline: 1.4073x; 1.1255x over previous
//
#include <hip/hip_runtime.h>
#include <hip/hip_bf16.h>
#include <cstdint>
#include <cstddef>

#define NN 50000
#define EE 800000
#define DD 128
#define NEG 0.2f
#define EPSL 1e-5f

// radix/bucket sort config
#define NB   392                 // pass-1 blocks, 2048 edges each (392*2048 >= EE), mult of 4
#define NBKT 196                 // buckets = dst>>8 (dst < 50000 -> 0..195)
#define HM   (NBKT * NB)         // hist matrix size (76832, mult of 4)

#define GROWS 64                 // rows per gemm block (4 waves x 16)

typedef __hip_bfloat16 bf16;
typedef short short8 __attribute__((ext_vector_type(8)));   // 8 bf16 = 4 VGPRs
typedef float f32x4 __attribute__((ext_vector_type(4)));

__device__ inline float bflo(unsigned u) { return __uint_as_float(u << 16); }
__device__ inline float bfhi(unsigned u) { return __uint_as_float(u & 0xffff0000u); }

__device__ inline unsigned short f2bf(float f) {
    __bf16 h = (__bf16)f;
    return __builtin_bit_cast(unsigned short, h);
}

__device__ inline void store4(float* Out, size_t idx, float4 v) {
    *(float4*)&Out[idx] = v;
}
__device__ inline void store4(bf16* Out, size_t idx, float4 v) {
    union { bf16 b[4]; ushort4 u; } cv;
    cv.b[0] = (bf16)v.x; cv.b[1] = (bf16)v.y; cv.b[2] = (bf16)v.z; cv.b[3] = (bf16)v.w;
    *(ushort4*)&Out[idx] = cv.u;
}

// ================= CSR build: MSD bucket sort (dense writes, no global atomics) ============

__global__ __launch_bounds__(256) void pack_hist_kernel(const int* __restrict__ ei,
                                                        unsigned* __restrict__ keys,
                                                        int* __restrict__ histG) {
    __shared__ int lh[NBKT];
    int tid = threadIdx.x;
    for (int t = tid; t < NBKT; t += 256) lh[t] = 0;
    __syncthreads();
    int base = blockIdx.x * 2048;
    #pragma unroll
    for (int j = 0; j < 8; ++j) {
        int i = base + j * 256 + tid;
        if (i < EE) {
            unsigned s = (unsigned)ei[i];
            unsigned d = (unsigned)ei[EE + i];
            keys[i] = (d << 16) | s;
            atomicAdd(&lh[d >> 8], 1);
        }
    }
    __syncthreads();
    for (int t = tid; t < NBKT; t += 256) histG[t * NB + blockIdx.x] = lh[t];
}

__global__ __launch_bounds__(1024) void scan_hist_kernel(const int* __restrict__ histG,
                                                         int* __restrict__ offs,
                                                         int* __restrict__ bstart) {
    __shared__ int wsum[16];
    __shared__ int carry_s;
    int tid = threadIdx.x, lane = tid & 63, wv = tid >> 6;
    if (tid == 0) carry_s = 0;
    __syncthreads();
    for (int base = 0; base < HM; base += 4096) {
        int i4 = base + tid * 4;
        int4 v = make_int4(0, 0, 0, 0);
        if (i4 + 3 < HM) v = *(const int4*)&histG[i4];
        else {
            if (i4 + 0 < HM) v.x = histG[i4 + 0];
            if (i4 + 1 < HM) v.y = histG[i4 + 1];
            if (i4 + 2 < HM) v.z = histG[i4 + 2];
            if (i4 + 3 < HM) v.w = histG[i4 + 3];
        }
        int tsum = v.x + v.y + v.z + v.w;
        int x = tsum;
        for (int off = 1; off < 64; off <<= 1) {
            int t = __shfl_up(x, off);
            if (lane >= off) x += t;
        }
        if (lane == 63) wsum[wv] = x;
        __syncthreads();
        if (wv == 0) {
            int s = (lane < 16) ? wsum[lane] : 0;
            for (int off = 1; off < 16; off <<= 1) {
                int t = __shfl_up(s, off);
                if (lane >= off) s += t;
            }
            if (lane < 16) wsum[lane] = s;
        }
        __syncthreads();
        int waveoff = (wv == 0) ? 0 : wsum[wv - 1];
        int carry = carry_s;
        int o0 = carry + waveoff + x - tsum;
        int o1 = o0 + v.x, o2 = o1 + v.y, o3 = o2 + v.z;
        if (i4 + 3 < HM) *(int4*)&offs[i4] = make_int4(o0, o1, o2, o3);
        else {
            if (i4 + 0 < HM) offs[i4 + 0] = o0;
            if (i4 + 1 < HM) offs[i4 + 1] = o1;
            if (i4 + 2 < HM) offs[i4 + 2] = o2;
            if (i4 + 3 < HM) offs[i4 + 3] = o3;
        }
        if (i4 < HM && (i4 % NB) == 0) bstart[i4 / NB] = o0;
        __syncthreads();
        if (tid == 0) carry_s += wsum[15];
        __syncthreads();
    }
    if (tid == 0) bstart[NBKT] = carry_s;   // == EE
}

__global__ __launch_bounds__(256) void scatter_pass1_kernel(const unsigned* __restrict__ keys,
                                                            const int* __restrict__ offs,
                                                            unsigned* __restrict__ tmp) {
    __shared__ int lofs[NBKT];
    int tid = threadIdx.x;
    for (int t = tid; t < NBKT; t += 256) lofs[t] = offs[t * NB + blockIdx.x];
    __syncthreads();
    int base = blockIdx.x * 2048;
    #pragma unroll
    for (int j = 0; j < 8; ++j) {
        int i = base + j * 256 + tid;
        if (i < EE) {
            unsigned key = keys[i];
            int pos = atomicAdd(&lofs[key >> 24], 1);
            tmp[pos] = key;
        }
    }
}

// counting sort by dst low byte; ALSO emits row_ptr (the scan IS row_ptr for this bucket)
__global__ __launch_bounds__(256) void bucket_sort_kernel(const unsigned* __restrict__ tmp,
                                                          const int* __restrict__ bstart,
                                                          unsigned* __restrict__ col,
                                                          int* __restrict__ row_ptr) {
    __shared__ int cnt[256];
    __shared__ int cpos[256];
    __shared__ int wtot[4];
    int tid = threadIdx.x, lane = tid & 63, wv = tid >> 6;
    int s0 = bstart[blockIdx.x], s1 = bstart[blockIdx.x + 1];
    cnt[tid] = 0;
    __syncthreads();
    for (int i = s0 + tid; i < s1; i += 256)
        atomicAdd(&cnt[(tmp[i] >> 16) & 0xFF], 1);
    __syncthreads();
    int v = cnt[tid];
    int x = v;
    for (int off = 1; off < 64; off <<= 1) {
        int t = __shfl_up(x, off);
        if (lane >= off) x += t;
    }
    if (lane == 63) wtot[wv] = x;
    __syncthreads();
    int add = 0;
    for (int k = 0; k < wv; ++k) add += wtot[k];
    int start = s0 + add + x - v;   // exclusive scan + bucket base == row start of this dst
    cpos[tid] = start;
    int d = blockIdx.x * 256 + tid;
    if (d <= NN) row_ptr[d] = start;  // row_ptr[NN]=EE lands here (all cnt beyond NN are 0)
    __syncthreads();
    for (int i = s0 + tid; i < s1; i += 256) {
        unsigned key = tmp[i];
        int pos = atomicAdd(&cpos[(key >> 16) & 0xFF], 1);
        col[pos] = key;
    }
}

// ================= MFMA GEMM (+optional fused LN1+relu) + attention dots ===================
template <int H, bool LN>
__global__ __launch_bounds__(256) void gemm_attn(const float* __restrict__ X,
                                                 const float* __restrict__ W,
                                                 const float* __restrict__ att_s,
                                                 const float* __restrict__ att_d,
                                                 const double* __restrict__ stats,
                                                 const float* __restrict__ lnw,
                                                 const float* __restrict__ lnb,
                                                 bf16* __restrict__ Hout,
                                                 float* __restrict__ a_src,
                                                 float* __restrict__ a_dst) {
    __shared__ __align__(16) char lds[(128 * 136 + 64 * 136) * 2];  // 52224 B
    unsigned short* Bt = (unsigned short*)lds;              // [128][136] n-major (W^T)
    unsigned short* As = (unsigned short*)(lds + 128 * 136 * 2);  // [64][136]
    float* Cs = (float*)lds;                                // [64][132] (reuse)

    int tid = threadIdx.x;
    int c = tid & 127, half = tid >> 7;
    int row0 = blockIdx.x * GROWS;

    float mean = 0.f, inv = 1.f, wc = 1.f, bc = 0.f;
    if (LN) {
        const double M = (double)NN * DD;
        double mean_d = stats[0] / M;
        double var_d = stats[1] / M - mean_d * mean_d;
        mean = (float)mean_d;
        inv = rsqrtf((float)var_d + EPSL);
        wc = lnw[c]; bc = lnb[c];
    }

    #pragma unroll 4
    for (int i = 0; i < 32; ++i) {
        int k0 = i * 4 + half * 2;
        float wa = W[(size_t)k0 * DD + c];
        float wb = W[(size_t)(k0 + 1) * DD + c];
        unsigned pk = (unsigned)f2bf(wa) | ((unsigned)f2bf(wb) << 16);
        *(unsigned*)&Bt[c * 136 + k0] = pk;
    }
    #pragma unroll 4
    for (int i = 0; i < 32; ++i) {
        int r = i * 2 + half;
        int row = row0 + r;
        float v = (row < NN) ? X[(size_t)row * DD + c] : 0.f;
        if (LN) v = fmaxf((v - mean) * inv * wc + bc, 0.f);
        As[r * 136 + c] = f2bf(v);
    }
    __syncthreads();

    int lane = tid & 63, w = tid >> 6;
    int l15 = lane & 15, quad = lane >> 4;
    f32x4 acc[8];
    #pragma unroll
    for (int t = 0; t < 8; ++t) acc[t] = 0.f;
    const unsigned short* Arow = As + (w * 16 + l15) * 136 + quad * 8;
    const unsigned short* Brow = Bt + l15 * 136 + quad * 8;
    #pragma unroll
    for (int ks = 0; ks < 4; ++ks) {
        short8 a = *(const short8*)(Arow + ks * 32);
        #pragma unroll
        for (int t = 0; t < 8; ++t) {
            short8 b = *(const short8*)(Brow + t * 16 * 136 + ks * 32);
            acc[t] = __builtin_amdgcn_mfma_f32_16x16x32_bf16(a, b, acc[t], 0, 0, 0);
        }
    }
    __syncthreads();

    #pragma unroll
    for (int t = 0; t < 8; ++t)
        #pragma unroll
        for (int r = 0; r < 4; ++r)
            Cs[(w * 16 + quad * 4 + r) * 132 + t * 16 + l15] = acc[t][r];

    float ds0[4] = {0.f, 0.f, 0.f, 0.f}, dd0[4] = {0.f, 0.f, 0.f, 0.f};
    float ds1[4] = {0.f, 0.f, 0.f, 0.f}, dd1[4] = {0.f, 0.f, 0.f, 0.f};
    #pragma unroll
    for (int t = 0; t < 8; ++t) {
        float as = att_s[t * 16 + l15];
        float ad = att_d[t * 16 + l15];
        if (H == 2 && t >= 4) {
            #pragma unroll
            for (int r = 0; r < 4; ++r) {
                ds1[r] = fmaf(acc[t][r], as, ds1[r]);
                dd1[r] = fmaf(acc[t][r], ad, dd1[r]);
            }
        } else {
            #pragma unroll
            for (int r = 0; r < 4; ++r) {
                ds0[r] = fmaf(acc[t][r], as, ds0[r]);
                dd0[r] = fmaf(acc[t][r], ad, dd0[r]);
            }
        }
    }
    #pragma unroll
    for (int off = 1; off < 16; off <<= 1) {
        #pragma unroll
        for (int r = 0; r < 4; ++r) {
            ds0[r] += __shfl_xor(ds0[r], off);
            dd0[r] += __shfl_xor(dd0[r], off);
            if (H == 2) { ds1[r] += __shfl_xor(ds1[r], off); dd1[r] += __shfl_xor(dd1[r], off); }
        }
    }
    if (l15 == 0) {
        #pragma unroll
        for (int r = 0; r < 4; ++r) {
            int row = row0 + w * 16 + quad * 4 + r;
            if (row < NN) {
                if (H == 2) {
                    a_src[row * 2 + 0] = ds0[r];
                    a_src[row * 2 + 1] = ds1[r];
                    a_dst[row * 2 + 0] = dd0[r];
                    a_dst[row * 2 + 1] = dd1[r];
                } else {
                    a_src[row] = ds0[r];
                    a_dst[row] = dd0[r];
                }
            }
        }
    }
    __syncthreads();

    unsigned short* Hp = (unsigned short*)Hout;
    #pragma unroll 4
    for (int i = 0; i < 32; ++i) {
        int r = i * 2 + half;
        int row = row0 + r;
        if (row < NN) Hp[(size_t)row * DD + c] = f2bf(Cs[r * 132 + c]);
    }
}

// ============ GAT softmax + aggregate: HALF-WAVE PER NODE, shuffle broadcast ==============
// 256 threads = 8 half-waves = 8 nodes/block. No LDS, no barriers.
// Lane j of a half-wave loads edge j's col + a_src, computes exp weight; all 32 lanes
// consume via __shfl(.,j,32). Each lane owns 4 consecutive channels (uint2 gather).
template <int H, typename OT>
__global__ __launch_bounds__(256) void gat_agg(const int* __restrict__ row_ptr,
                                               const unsigned* __restrict__ col,
                                               const bf16* __restrict__ Hin,
                                               const float* __restrict__ a_src,
                                               const float* __restrict__ a_dst,
                                               const float* __restrict__ bias,
                                               OT* __restrict__ Out,
                                               float2* __restrict__ pstats) {
    int tid = threadIdx.x;
    int sl = tid & 31;
    int n = blockIdx.x * 8 + (tid >> 5);
    int c0 = sl * 4;
    const int head4 = (H == 2) ? (sl >> 4) : 0;

    int beg = row_ptr[n], end = row_ptr[n + 1];
    int deg = end - beg;

    float ad0 = a_dst[n * H + 0];
    float ad1 = (H == 2) ? a_dst[n * H + 1] : 0.f;
    const ushort* Hp = (const ushort*)Hin + c0;

    float acc[4] = {0.f, 0.f, 0.f, 0.f};
    float dl0 = 0.f, dl1 = 0.f;

    for (int base = 0; base < deg; base += 32) {
        int ecnt = min(32, deg - base);
        int sv = 0; float w0v = 0.f, w1v = 0.f;
        if (sl < ecnt) {
            sv = (int)(col[beg + base + sl] & 0xffffu);
            if (H == 2) {
                float2 av = *(const float2*)&a_src[sv * 2];
                float e0 = av.x + ad0; e0 = (e0 > 0.f) ? e0 : NEG * e0;
                float e1 = av.y + ad1; e1 = (e1 > 0.f) ? e1 : NEG * e1;
                w0v = __expf(e0); w1v = __expf(e1);
                dl0 += w0v; dl1 += w1v;
            } else {
                float e0 = a_src[sv] + ad0; e0 = (e0 > 0.f) ? e0 : NEG * e0;
                w0v = __expf(e0);
                dl0 += w0v;
            }
        }
        int j = 0;
        for (; j + 3 < ecnt; j += 4) {
            int s0 = __shfl(sv, j, 32), s1 = __shfl(sv, j + 1, 32);
            int s2 = __shfl(sv, j + 2, 32), s3 = __shfl(sv, j + 3, 32);
            float wa, wb, wc2, wd;
            if (H == 2) {
                float a0 = __shfl(w0v, j, 32),     b0 = __shfl(w1v, j, 32);
                float a1 = __shfl(w0v, j + 1, 32), b1 = __shfl(w1v, j + 1, 32);
                float a2 = __shfl(w0v, j + 2, 32), b2 = __shfl(w1v, j + 2, 32);
                float a3 = __shfl(w0v, j + 3, 32), b3 = __shfl(w1v, j + 3, 32);
                wa = head4 ? b0 : a0; wb = head4 ? b1 : a1;
                wc2 = head4 ? b2 : a2; wd = head4 ? b3 : a3;
            } else {
                wa = __shfl(w0v, j, 32); wb = __shfl(w0v, j + 1, 32);
                wc2 = __shfl(w0v, j + 2, 32); wd = __shfl(w0v, j + 3, 32);
            }
            uint2 h0 = *(const uint2*)(Hp + (size_t)s0 * DD);
            uint2 h1 = *(const uint2*)(Hp + (size_t)s1 * DD);
            uint2 h2 = *(const uint2*)(Hp + (size_t)s2 * DD);
            uint2 h3 = *(const uint2*)(Hp + (size_t)s3 * DD);
            acc[0] = fmaf(wa, bflo(h0.x), acc[0]); acc[1] = fmaf(wa, bfhi(h0.x), acc[1]);
            acc[2] = fmaf(wa, bflo(h0.y), acc[2]); acc[3] = fmaf(wa, bfhi(h0.y), acc[3]);
            acc[0] = fmaf(wb, bflo(h1.x), acc[0]); acc[1] = fmaf(wb, bfhi(h1.x), acc[1]);
            acc[2] = fmaf(wb, bflo(h1.y), acc[2]); acc[3] = fmaf(wb, bfhi(h1.y), acc[3]);
            acc[0] = fmaf(wc2, bflo(h2.x), acc[0]); acc[1] = fmaf(wc2, bfhi(h2.x), acc[1]);
            acc[2] = fmaf(wc2, bflo(h2.y), acc[2]); acc[3] = fmaf(wc2, bfhi(h2.y), acc[3]);
            acc[0] = fmaf(wd, bflo(h3.x), acc[0]); acc[1] = fmaf(wd, bfhi(h3.x), acc[1]);
            acc[2] = fmaf(wd, bflo(h3.y), acc[2]); acc[3] = fmaf(wd, bfhi(h3.y), acc[3]);
        }
        for (; j < ecnt; ++j) {
            int s = __shfl(sv, j, 32);
            float w;
            if (H == 2) {
                float a0 = __shfl(w0v, j, 32), b0 = __shfl(w1v, j, 32);
                w = head4 ? b0 : a0;
            } else {
                w = __shfl(w0v, j, 32);
            }
            uint2 hv = *(const uint2*)(Hp + (size_t)s * DD);
            acc[0] = fmaf(w, bflo(hv.x), acc[0]); acc[1] = fmaf(w, bfhi(hv.x), acc[1]);
            acc[2] = fmaf(w, bflo(hv.y), acc[2]); acc[3] = fmaf(w, bfhi(hv.y), acc[3]);
        }
    }

    // denominator reduce within half-wave (offsets <32 keep halves closed)
    #pragma unroll
    for (int off = 1; off < 32; off <<= 1) {
        dl0 += __shfl_xor(dl0, off);
        if (H == 2) dl1 += __shfl_xor(dl1, off);
    }

    // implicit self-loop
    float e0 = a_src[n * H + 0] + ad0; e0 = (e0 > 0.f) ? e0 : NEG * e0;
    float ws0 = __expf(e0);
    float ws1 = 0.f;
    if (H == 2) {
        float e1 = a_src[n * H + 1] + ad1; e1 = (e1 > 0.f) ? e1 : NEG * e1;
        ws1 = __expf(e1);
    }
    float den = (H == 2 && head4) ? (dl1 + ws1) : (dl0 + ws0);
    float wself = (H == 2 && head4) ? ws1 : ws0;
    float rinv = 1.f / (den + 1e-16f);
    uint2 hs = *(const uint2*)(Hp + (size_t)n * DD);   // own row, coalesced
    float4 bi = *(const float4*)&bias[c0];
    float4 o;
    o.x = fmaf(wself, bflo(hs.x), acc[0]) * rinv + bi.x;
    o.y = fmaf(wself, bfhi(hs.x), acc[1]) * rinv + bi.y;
    o.z = fmaf(wself, bflo(hs.y), acc[2]) * rinv + bi.z;
    o.w = fmaf(wself, bfhi(hs.y), acc[3]) * rinv + bi.w;
    store4(Out, (size_t)n * DD + c0, o);

    // LN partials (per node) via half-wave reduce
    float t1 = o.x + o.y + o.z + o.w;
    float t2 = o.x * o.x + o.y * o.y + o.z * o.z + o.w * o.w;
    #pragma unroll
    for (int off = 1; off < 32; off <<= 1) {
        t1 += __shfl_xor(t1, off);
        t2 += __shfl_xor(t2, off);
    }
    if (sl == 0) pstats[n] = make_float2(t1, t2);
}

// ---------------- deterministic single-block reduce of per-node LN partials ----------------
__global__ __launch_bounds__(1024) void reduce_stats_kernel(const float2* __restrict__ pstats,
                                                            double* __restrict__ stats) {
    int tid = threadIdx.x, lane = tid & 63, wv = tid >> 6;
    double s1 = 0.0, s2 = 0.0;
    for (int i = tid; i < NN; i += 1024) {
        float2 v = pstats[i];
        s1 += (double)v.x; s2 += (double)v.y;
    }
    for (int off = 32; off; off >>= 1) {
        s1 += __shfl_xor(s1, off);
        s2 += __shfl_xor(s2, off);
    }
    __shared__ double w1[16], w2[16];
    if (lane == 0) { w1[wv] = s1; w2[wv] = s2; }
    __syncthreads();
    if (tid == 0) {
        double a = 0.0, b = 0.0;
        for (int i = 0; i < 16; ++i) { a += w1[i]; b += w2[i]; }
        stats[0] = a; stats[1] = b;
    }
}

// ======== SimpleConv(mean) + LN2 affine + residual + relu: half-wave per node =============
__global__ __launch_bounds__(256) void simpleconv_kernel(const int* __restrict__ row_ptr,
                                                         const unsigned* __restrict__ col,
                                                         const bf16* __restrict__ Hin,
                                                         const float* __restrict__ X,
                                                         const double* __restrict__ stats,
                                                         const float* __restrict__ lnw,
                                                         const float* __restrict__ lnb,
                                                         float* __restrict__ Out) {
    int tid = threadIdx.x;
    int sl = tid & 31;
    int n = blockIdx.x * 8 + (tid >> 5);
    int c0 = sl * 4;
    int beg = row_ptr[n], end = row_ptr[n + 1];
    int deg = end - beg;
    const ushort* Hp = (const ushort*)Hin + c0;

    float acc[4] = {0.f, 0.f, 0.f, 0.f};
    for (int base = 0; base < deg; base += 32) {
        int ecnt = min(32, deg - base);
        int sv = 0;
        if (sl < ecnt) sv = (int)(col[beg + base + sl] & 0xffffu);
        int j = 0;
        for (; j + 3 < ecnt; j += 4) {
            int s0 = __shfl(sv, j, 32), s1 = __shfl(sv, j + 1, 32);
            int s2 = __shfl(sv, j + 2, 32), s3 = __shfl(sv, j + 3, 32);
            uint2 h0 = *(const uint2*)(Hp + (size_t)s0 * DD);
            uint2 h1 = *(const uint2*)(Hp + (size_t)s1 * DD);
            uint2 h2 = *(const uint2*)(Hp + (size_t)s2 * DD);
            uint2 h3 = *(const uint2*)(Hp + (size_t)s3 * DD);
            acc[0] += bflo(h0.x) + bflo(h1.x) + bflo(h2.x) + bflo(h3.x);
            acc[1] += bfhi(h0.x) + bfhi(h1.x) + bfhi(h2.x) + bfhi(h3.x);
            acc[2] += bflo(h0.y) + bflo(h1.y) + bflo(h2.y) + bflo(h3.y);
            acc[3] += bfhi(h0.y) + bfhi(h1.y) + bfhi(h2.y) + bfhi(h3.y);
        }
        for (; j < ecnt; ++j) {
            int s = __shfl(sv, j, 32);
            uint2 hv = *(const uint2*)(Hp + (size_t)s * DD);
            acc[0] += bflo(hv.x); acc[1] += bfhi(hv.x);
            acc[2] += bflo(hv.y); acc[3] += bfhi(hv.y);
        }
    }

    const double M = (double)NN * DD;
    double mean_d = stats[0] / M;
    double var_d = stats[1] / M - mean_d * mean_d;
    float mean2 = (float)mean_d;
    float inv2 = rsqrtf((float)var_d + EPSL);
    float rc = 1.f / (float)((deg > 0) ? deg : 1);
    float4 xr = *(const float4*)&X[(size_t)n * DD + c0];
    float4 o;
    if (deg > 0) {
        float4 lw = *(const float4*)&lnw[c0];
        float4 lb = *(const float4*)&lnb[c0];
        o.x = (acc[0] * rc - mean2) * inv2 * lw.x + lb.x;
        o.y = (acc[1] * rc - mean2) * inv2 * lw.y + lb.y;
        o.z = (acc[2] * rc - mean2) * inv2 * lw.z + lb.z;
        o.w = (acc[3] * rc - mean2) * inv2 * lw.w + lb.w;
    } else {
        o.x = o.y = o.z = o.w = 0.f;
    }
    o.x = fmaxf(o.x + xr.x, 0.f);
    o.y = fmaxf(o.y + xr.y, 0.f);
    o.z = fmaxf(o.z + xr.z, 0.f);
    o.w = fmaxf(o.w + xr.w, 0.f);
    *(float4*)&Out[(size_t)n * DD + c0] = o;
}

extern "C" void kernel_launch(void* const* d_in, const int* in_sizes, int n_in,
                              void* d_out, int out_size, void* d_ws, size_t ws_size,
                              hipStream_t stream) {
    const float* x    = (const float*)d_in[0];
    const int*   ei   = (const int*)d_in[1];
    const float* W1   = (const float*)d_in[2];
    const float* as1  = (const float*)d_in[3];
    const float* ad1  = (const float*)d_in[4];
    const float* b1   = (const float*)d_in[5];
    const float* ln1w = (const float*)d_in[6];
    const float* ln1b = (const float*)d_in[7];
    const float* W2   = (const float*)d_in[8];
    const float* as2  = (const float*)d_in[9];
    const float* ad2  = (const float*)d_in[10];
    const float* b2   = (const float*)d_in[11];
    const float* ln2w = (const float*)d_in[12];
    const float* ln2b = (const float*)d_in[13];
    float* out = (float*)d_out;

    char* p = (char*)d_ws;
    auto alloc = [&](size_t bytes) {
        void* r = (void*)p;
        p += (bytes + 255) & ~(size_t)255;
        return r;
    };
    unsigned* keys    = (unsigned*)alloc((size_t)EE * 4);
    unsigned* tmp     = (unsigned*)alloc((size_t)EE * 4);
    unsigned* col     = (unsigned*)alloc((size_t)EE * 4);
    int*      histG   = (int*)alloc((size_t)HM * 4);
    int*      offs    = (int*)alloc((size_t)HM * 4);
    int*      bstart  = (int*)alloc((size_t)(NBKT + 1) * 4);
    int*      row_ptr = (int*)alloc((size_t)(NN + 256) * 4);
    double*   stats1  = (double*)alloc(16);
    double*   stats2  = (double*)alloc(16);
    float2*   pstats  = (float2*)alloc((size_t)NN * 8);
    bf16*     bufH    = (bf16*)alloc((size_t)NN * DD * 2);   // h1, later h2 (bf16, gathered)
    float*    bufF    = (float*)alloc((size_t)NN * DD * 4);  // out1 fp32; later out2 bf16 alias
    bf16*     out2    = (bf16*)bufF;
    float*    aS1     = (float*)alloc((size_t)NN * 2 * 4);
    float*    aD1     = (float*)alloc((size_t)NN * 2 * 4);
    float*    aS2     = (float*)alloc((size_t)NN * 4);
    float*    aD2     = (float*)alloc((size_t)NN * 4);

    // ---- CSR build (bucket sort, dense writes; row_ptr fused into pass 2) ----
    pack_hist_kernel<<<NB, 256, 0, stream>>>(ei, keys, histG);
    scan_hist_kernel<<<1, 1024, 0, stream>>>(histG, offs, bstart);
    scatter_pass1_kernel<<<NB, 256, 0, stream>>>(keys, offs, tmp);
    bucket_sort_kernel<<<NBKT, 256, 0, stream>>>(tmp, bstart, col, row_ptr);

    const int GB = (NN + GROWS - 1) / GROWS;   // 782
    const int AB = NN / 8;                     // 6250 (exact)

    // layer 1: GATConv(128 -> 64, heads=2, concat); LN1+relu deferred into next gemm
    gemm_attn<2, false><<<GB, 256, 0, stream>>>(x, W1, as1, ad1,
                                                nullptr, nullptr, nullptr,
                                                bufH, aS1, aD1);
    gat_agg<2, float><<<AB, 256, 0, stream>>>(row_ptr, col, bufH, aS1, aD1, b1, bufF, pstats);
    reduce_stats_kernel<<<1, 1024, 0, stream>>>(pstats, stats1);

    // layer 2: GATConv(128 -> 128, heads=1), input = relu(ln1(out1)) fused into gemm
    gemm_attn<1, true><<<GB, 256, 0, stream>>>(bufF, W2, as2, ad2,
                                               stats1, ln1w, ln1b,
                                               bufH, aS2, aD2);
    gat_agg<1, bf16><<<AB, 256, 0, stream>>>(row_ptr, col, bufH, aS2, aD2, b2, out2, pstats);
    reduce_stats_kernel<<<1, 1024, 0, stream>>>(pstats, stats2);

    // SimpleConv mean over original edges + LN2 affine + residual + relu (fused)
    simpleconv_kernel<<<AB, 256, 0, stream>>>(row_ptr, col, out2, x,
                                              stats2, ln2w, ln2b, out);
}

// Round 10
// 321.349 us; speedup vs baseline: 1.4837x; 1.0543x over previous
//
#include <hip/hip_runtime.h>
#include <hip/hip_bf16.h>
#include <cstdint>
#include <cstddef>

#define NN 50000
#define EE 800000
#define DD 128
#define NEG 0.2f
#define EPSL 1e-5f

// radix/bucket sort config
#define NB   392                 // pass-1 blocks, 2048 edges each
#define NBKT 196                 // buckets = dst>>8
#define HM   (NBKT * NB)

#define GROWS 64                 // rows per gemm block

typedef __hip_bfloat16 bf16;
typedef short short8 __attribute__((ext_vector_type(8)));
typedef float f32x4 __attribute__((ext_vector_type(4)));

__device__ inline float bflo(unsigned u) { return __uint_as_float(u << 16); }
__device__ inline float bfhi(unsigned u) { return __uint_as_float(u & 0xffff0000u); }

__device__ inline unsigned short f2bf(float f) {
    __bf16 h = (__bf16)f;
    return __builtin_bit_cast(unsigned short, h);
}

__device__ inline void store4(float* Out, size_t idx, float4 v) {
    *(float4*)&Out[idx] = v;
}
__device__ inline void store4(bf16* Out, size_t idx, float4 v) {
    union { bf16 b[4]; ushort4 u; } cv;
    cv.b[0] = (bf16)v.x; cv.b[1] = (bf16)v.y; cv.b[2] = (bf16)v.z; cv.b[3] = (bf16)v.w;
    *(ushort4*)&Out[idx] = cv.u;
}

// ================= CSR build: MSD bucket sort (dense writes, no global atomics) ============

__global__ __launch_bounds__(256) void pack_hist_kernel(const int* __restrict__ ei,
                                                        unsigned* __restrict__ keys,
                                                        int* __restrict__ histG) {
    __shared__ int lh[NBKT];
    int tid = threadIdx.x;
    for (int t = tid; t < NBKT; t += 256) lh[t] = 0;
    __syncthreads();
    int base = blockIdx.x * 2048;
    #pragma unroll
    for (int j = 0; j < 8; ++j) {
        int i = base + j * 256 + tid;
        if (i < EE) {
            unsigned s = (unsigned)ei[i];
            unsigned d = (unsigned)ei[EE + i];
            keys[i] = (d << 16) | s;
            atomicAdd(&lh[d >> 8], 1);
        }
    }
    __syncthreads();
    for (int t = tid; t < NBKT; t += 256) histG[t * NB + blockIdx.x] = lh[t];
}

__global__ __launch_bounds__(1024) void scan_hist_kernel(const int* __restrict__ histG,
                                                         int* __restrict__ offs,
                                                         int* __restrict__ bstart) {
    __shared__ int wsum[16];
    __shared__ int carry_s;
    int tid = threadIdx.x, lane = tid & 63, wv = tid >> 6;
    if (tid == 0) carry_s = 0;
    __syncthreads();
    for (int base = 0; base < HM; base += 4096) {
        int i4 = base + tid * 4;
        int4 v = make_int4(0, 0, 0, 0);
        if (i4 + 3 < HM) v = *(const int4*)&histG[i4];
        else {
            if (i4 + 0 < HM) v.x = histG[i4 + 0];
            if (i4 + 1 < HM) v.y = histG[i4 + 1];
            if (i4 + 2 < HM) v.z = histG[i4 + 2];
            if (i4 + 3 < HM) v.w = histG[i4 + 3];
        }
        int tsum = v.x + v.y + v.z + v.w;
        int x = tsum;
        for (int off = 1; off < 64; off <<= 1) {
            int t = __shfl_up(x, off);
            if (lane >= off) x += t;
        }
        if (lane == 63) wsum[wv] = x;
        __syncthreads();
        if (wv == 0) {
            int s = (lane < 16) ? wsum[lane] : 0;
            for (int off = 1; off < 16; off <<= 1) {
                int t = __shfl_up(s, off);
                if (lane >= off) s += t;
            }
            if (lane < 16) wsum[lane] = s;
        }
        __syncthreads();
        int waveoff = (wv == 0) ? 0 : wsum[wv - 1];
        int carry = carry_s;
        int o0 = carry + waveoff + x - tsum;
        int o1 = o0 + v.x, o2 = o1 + v.y, o3 = o2 + v.z;
        if (i4 + 3 < HM) *(int4*)&offs[i4] = make_int4(o0, o1, o2, o3);
        else {
            if (i4 + 0 < HM) offs[i4 + 0] = o0;
            if (i4 + 1 < HM) offs[i4 + 1] = o1;
            if (i4 + 2 < HM) offs[i4 + 2] = o2;
            if (i4 + 3 < HM) offs[i4 + 3] = o3;
        }
        if (i4 < HM && (i4 % NB) == 0) bstart[i4 / NB] = o0;
        __syncthreads();
        if (tid == 0) carry_s += wsum[15];
        __syncthreads();
    }
    if (tid == 0) bstart[NBKT] = carry_s;   // == EE
}

__global__ __launch_bounds__(256) void scatter_pass1_kernel(const unsigned* __restrict__ keys,
                                                            const int* __restrict__ offs,
                                                            unsigned* __restrict__ tmp) {
    __shared__ int lofs[NBKT];
    int tid = threadIdx.x;
    for (int t = tid; t < NBKT; t += 256) lofs[t] = offs[t * NB + blockIdx.x];
    __syncthreads();
    int base = blockIdx.x * 2048;
    #pragma unroll
    for (int j = 0; j < 8; ++j) {
        int i = base + j * 256 + tid;
        if (i < EE) {
            unsigned key = keys[i];
            int pos = atomicAdd(&lofs[key >> 24], 1);
            tmp[pos] = key;
        }
    }
}

// counting sort by dst low byte; ALSO emits row_ptr (the scan IS row_ptr for this bucket)
__global__ __launch_bounds__(256) void bucket_sort_kernel(const unsigned* __restrict__ tmp,
                                                          const int* __restrict__ bstart,
                                                          unsigned* __restrict__ col,
                                                          int* __restrict__ row_ptr) {
    __shared__ int cnt[256];
    __shared__ int cpos[256];
    __shared__ int wtot[4];
    int tid = threadIdx.x, lane = tid & 63, wv = tid >> 6;
    int s0 = bstart[blockIdx.x], s1 = bstart[blockIdx.x + 1];
    cnt[tid] = 0;
    __syncthreads();
    for (int i = s0 + tid; i < s1; i += 256)
        atomicAdd(&cnt[(tmp[i] >> 16) & 0xFF], 1);
    __syncthreads();
    int v = cnt[tid];
    int x = v;
    for (int off = 1; off < 64; off <<= 1) {
        int t = __shfl_up(x, off);
        if (lane >= off) x += t;
    }
    if (lane == 63) wtot[wv] = x;
    __syncthreads();
    int add = 0;
    for (int k = 0; k < wv; ++k) add += wtot[k];
    int start = s0 + add + x - v;
    cpos[tid] = start;
    int d = blockIdx.x * 256 + tid;
    if (d <= NN) row_ptr[d] = start;
    __syncthreads();
    for (int i = s0 + tid; i < s1; i += 256) {
        unsigned key = tmp[i];
        int pos = atomicAdd(&cpos[(key >> 16) & 0xFF], 1);
        col[pos] = key;
    }
}

// ================= MFMA GEMM (+optional fused LN1+relu) + attention dots ===================
// 512 threads = 8 waves; 64 rows/block. Wave w: rows (w&3)*16..+16, cols (w>>2)*64..+64.
// mfma_f32_16x16x32_bf16 layouts (HW-verified): A[m=lane&15][k=quad*8+j],
// B[n=lane&15][k=quad*8+j], C/D col=lane&15, row=quad*4+reg.
template <int H, bool LN>
__global__ __launch_bounds__(512) void gemm_attn(const float* __restrict__ X,
                                                 const float* __restrict__ W,
                                                 const float* __restrict__ att_s,
                                                 const float* __restrict__ att_d,
                                                 const double* __restrict__ stats,
                                                 const float* __restrict__ lnw,
                                                 const float* __restrict__ lnb,
                                                 bf16* __restrict__ Hout,
                                                 float* __restrict__ a_src,
                                                 float* __restrict__ a_dst) {
    __shared__ __align__(16) char lds[(128 * 136 + 64 * 136) * 2 + 2048];  // 54272 B
    unsigned short* Bt = (unsigned short*)lds;                    // [128][136] (W^T)
    unsigned short* As = (unsigned short*)(lds + 128 * 136 * 2);  // [64][136]
    float* Cs = (float*)lds;                                      // [64][132] (reuse)
    float* psum = (float*)(lds + (128 * 136 + 64 * 136) * 2);     // [256] (H==1 combine)

    int tid = threadIdx.x;
    int c = tid & 127, h4 = tid >> 7;     // h4 in 0..3
    int row0 = blockIdx.x * GROWS;

    float mean = 0.f, inv = 1.f, wc = 1.f, bc = 0.f;
    if (LN) {
        const double M = (double)NN * DD;
        double mean_d = stats[0] / M;
        double var_d = stats[1] / M - mean_d * mean_d;
        mean = (float)mean_d;
        inv = rsqrtf((float)var_d + EPSL);
        wc = lnw[c]; bc = lnb[c];
    }

    // stage W -> Bt transposed (pairs of k per b32 write): 16 pairs/thread
    #pragma unroll 4
    for (int i = 0; i < 16; ++i) {
        int k0 = (i * 4 + h4) * 2;
        float wa = W[(size_t)k0 * DD + c];
        float wb = W[(size_t)(k0 + 1) * DD + c];
        unsigned pk = (unsigned)f2bf(wa) | ((unsigned)f2bf(wb) << 16);
        *(unsigned*)&Bt[c * 136 + k0] = pk;
    }
    // stage X (+LN+relu) -> As: 16 rows/thread-group
    #pragma unroll 4
    for (int i = 0; i < 16; ++i) {
        int r = i * 4 + h4;
        int row = row0 + r;
        float v = (row < NN) ? X[(size_t)row * DD + c] : 0.f;
        if (LN) v = fmaxf((v - mean) * inv * wc + bc, 0.f);
        As[r * 136 + c] = f2bf(v);
    }
    __syncthreads();

    int lane = tid & 63, w = tid >> 6;    // 8 waves
    int rg = w & 3, cg = w >> 2;          // row-group, col-group
    int l15 = lane & 15, quad = lane >> 4;
    f32x4 acc[4];
    #pragma unroll
    for (int t = 0; t < 4; ++t) acc[t] = 0.f;
    const unsigned short* Arow = As + (rg * 16 + l15) * 136 + quad * 8;
    const unsigned short* Brow = Bt + l15 * 136 + quad * 8;
    #pragma unroll
    for (int ks = 0; ks < 4; ++ks) {
        short8 a = *(const short8*)(Arow + ks * 32);
        #pragma unroll
        for (int tt = 0; tt < 4; ++tt) {
            short8 b = *(const short8*)(Brow + (cg * 4 + tt) * 16 * 136 + ks * 32);
            acc[tt] = __builtin_amdgcn_mfma_f32_16x16x32_bf16(a, b, acc[tt], 0, 0, 0);
        }
    }
    __syncthreads();   // all waves done reading Bt/As; Cs may overwrite

    #pragma unroll
    for (int tt = 0; tt < 4; ++tt)
        #pragma unroll
        for (int r = 0; r < 4; ++r)
            Cs[(rg * 16 + quad * 4 + r) * 132 + (cg * 4 + tt) * 16 + l15] = acc[tt][r];

    // attention dots: wave covers cols (cg*4+tt)*16+l15; for H=2 head == cg exactly
    float ds[4] = {0.f, 0.f, 0.f, 0.f}, dd[4] = {0.f, 0.f, 0.f, 0.f};
    #pragma unroll
    for (int tt = 0; tt < 4; ++tt) {
        int cc = (cg * 4 + tt) * 16 + l15;
        float as_ = att_s[cc], ad_ = att_d[cc];
        #pragma unroll
        for (int r = 0; r < 4; ++r) {
            ds[r] = fmaf(acc[tt][r], as_, ds[r]);
            dd[r] = fmaf(acc[tt][r], ad_, dd[r]);
        }
    }
    #pragma unroll
    for (int off = 1; off < 16; off <<= 1) {
        #pragma unroll
        for (int r = 0; r < 4; ++r) {
            ds[r] += __shfl_xor(ds[r], off);
            dd[r] += __shfl_xor(dd[r], off);
        }
    }
    if (l15 == 0) {
        #pragma unroll
        for (int r = 0; r < 4; ++r) {
            int rr = rg * 16 + quad * 4 + r;
            int row = row0 + rr;
            if (H == 2) {
                if (row < NN) {
                    a_src[row * 2 + cg] = ds[r];
                    a_dst[row * 2 + cg] = dd[r];
                }
            } else {
                psum[cg * 64 + rr] = ds[r];          // [0..127]: src partials
                psum[128 + cg * 64 + rr] = dd[r];    // [128..255]: dst partials
            }
        }
    }
    __syncthreads();

    if (H == 1 && tid < 64) {
        int row = row0 + tid;
        if (row < NN) {
            a_src[row] = psum[tid] + psum[64 + tid];
            a_dst[row] = psum[128 + tid] + psum[192 + tid];
        }
    }

    // coalesced bf16 row stores
    unsigned short* Hp = (unsigned short*)Hout;
    #pragma unroll 4
    for (int i = 0; i < 16; ++i) {
        int r = i * 4 + h4;
        int row = row0 + r;
        if (row < NN) Hp[(size_t)row * DD + c] = f2bf(Cs[r * 132 + c]);
    }
}

// ============ GAT softmax + aggregate: HALF-WAVE PER NODE, shuffle broadcast ==============
template <int H, typename OT>
__global__ __launch_bounds__(256) void gat_agg(const int* __restrict__ row_ptr,
                                               const unsigned* __restrict__ col,
                                               const bf16* __restrict__ Hin,
                                               const float* __restrict__ a_src,
                                               const float* __restrict__ a_dst,
                                               const float* __restrict__ bias,
                                               OT* __restrict__ Out,
                                               float2* __restrict__ pstats) {
    int tid = threadIdx.x;
    int sl = tid & 31;
    int n = blockIdx.x * 8 + (tid >> 5);
    int c0 = sl * 4;
    const int head4 = (H == 2) ? (sl >> 4) : 0;

    int beg = row_ptr[n], end = row_ptr[n + 1];
    int deg = end - beg;

    float ad0 = a_dst[n * H + 0];
    float ad1 = (H == 2) ? a_dst[n * H + 1] : 0.f;
    const ushort* Hp = (const ushort*)Hin + c0;

    float acc[4] = {0.f, 0.f, 0.f, 0.f};
    float dl0 = 0.f, dl1 = 0.f;

    for (int base = 0; base < deg; base += 32) {
        int ecnt = min(32, deg - base);
        int sv = 0; float w0v = 0.f, w1v = 0.f;
        if (sl < ecnt) {
            sv = (int)(col[beg + base + sl] & 0xffffu);
            if (H == 2) {
                float2 av = *(const float2*)&a_src[sv * 2];
                float e0 = av.x + ad0; e0 = (e0 > 0.f) ? e0 : NEG * e0;
                float e1 = av.y + ad1; e1 = (e1 > 0.f) ? e1 : NEG * e1;
                w0v = __expf(e0); w1v = __expf(e1);
                dl0 += w0v; dl1 += w1v;
            } else {
                float e0 = a_src[sv] + ad0; e0 = (e0 > 0.f) ? e0 : NEG * e0;
                w0v = __expf(e0);
                dl0 += w0v;
            }
        }
        int j = 0;
        for (; j + 7 < ecnt; j += 8) {
            int s[8]; float ww[8];
            uint2 h[8];
            #pragma unroll
            for (int u = 0; u < 8; ++u) {
                s[u] = __shfl(sv, j + u, 32);
                if (H == 2) {
                    float a0 = __shfl(w0v, j + u, 32), b0 = __shfl(w1v, j + u, 32);
                    ww[u] = head4 ? b0 : a0;
                } else {
                    ww[u] = __shfl(w0v, j + u, 32);
                }
            }
            #pragma unroll
            for (int u = 0; u < 8; ++u) h[u] = *(const uint2*)(Hp + (size_t)s[u] * DD);
            #pragma unroll
            for (int u = 0; u < 8; ++u) {
                acc[0] = fmaf(ww[u], bflo(h[u].x), acc[0]);
                acc[1] = fmaf(ww[u], bfhi(h[u].x), acc[1]);
                acc[2] = fmaf(ww[u], bflo(h[u].y), acc[2]);
                acc[3] = fmaf(ww[u], bfhi(h[u].y), acc[3]);
            }
        }
        for (; j < ecnt; ++j) {
            int s = __shfl(sv, j, 32);
            float w;
            if (H == 2) {
                float a0 = __shfl(w0v, j, 32), b0 = __shfl(w1v, j, 32);
                w = head4 ? b0 : a0;
            } else {
                w = __shfl(w0v, j, 32);
            }
            uint2 hv = *(const uint2*)(Hp + (size_t)s * DD);
            acc[0] = fmaf(w, bflo(hv.x), acc[0]); acc[1] = fmaf(w, bfhi(hv.x), acc[1]);
            acc[2] = fmaf(w, bflo(hv.y), acc[2]); acc[3] = fmaf(w, bfhi(hv.y), acc[3]);
        }
    }

    #pragma unroll
    for (int off = 1; off < 32; off <<= 1) {
        dl0 += __shfl_xor(dl0, off);
        if (H == 2) dl1 += __shfl_xor(dl1, off);
    }

    // implicit self-loop
    float e0 = a_src[n * H + 0] + ad0; e0 = (e0 > 0.f) ? e0 : NEG * e0;
    float ws0 = __expf(e0);
    float ws1 = 0.f;
    if (H == 2) {
        float e1 = a_src[n * H + 1] + ad1; e1 = (e1 > 0.f) ? e1 : NEG * e1;
        ws1 = __expf(e1);
    }
    float den = (H == 2 && head4) ? (dl1 + ws1) : (dl0 + ws0);
    float wself = (H == 2 && head4) ? ws1 : ws0;
    float rinv = 1.f / (den + 1e-16f);
    uint2 hs = *(const uint2*)(Hp + (size_t)n * DD);
    float4 bi = *(const float4*)&bias[c0];
    float4 o;
    o.x = fmaf(wself, bflo(hs.x), acc[0]) * rinv + bi.x;
    o.y = fmaf(wself, bfhi(hs.x), acc[1]) * rinv + bi.y;
    o.z = fmaf(wself, bflo(hs.y), acc[2]) * rinv + bi.z;
    o.w = fmaf(wself, bfhi(hs.y), acc[3]) * rinv + bi.w;
    store4(Out, (size_t)n * DD + c0, o);

    float t1 = o.x + o.y + o.z + o.w;
    float t2 = o.x * o.x + o.y * o.y + o.z * o.z + o.w * o.w;
    #pragma unroll
    for (int off = 1; off < 32; off <<= 1) {
        t1 += __shfl_xor(t1, off);
        t2 += __shfl_xor(t2, off);
    }
    if (sl == 0) pstats[n] = make_float2(t1, t2);
}

// ---------------- deterministic single-block reduce of per-node LN partials ----------------
__global__ __launch_bounds__(1024) void reduce_stats_kernel(const float2* __restrict__ pstats,
                                                            double* __restrict__ stats) {
    int tid = threadIdx.x, lane = tid & 63, wv = tid >> 6;
    double s1 = 0.0, s2 = 0.0;
    for (int i = tid; i < NN; i += 1024) {
        float2 v = pstats[i];
        s1 += (double)v.x; s2 += (double)v.y;
    }
    for (int off = 32; off; off >>= 1) {
        s1 += __shfl_xor(s1, off);
        s2 += __shfl_xor(s2, off);
    }
    __shared__ double w1[16], w2[16];
    if (lane == 0) { w1[wv] = s1; w2[wv] = s2; }
    __syncthreads();
    if (tid == 0) {
        double a = 0.0, b = 0.0;
        for (int i = 0; i < 16; ++i) { a += w1[i]; b += w2[i]; }
        stats[0] = a; stats[1] = b;
    }
}

// ======== SimpleConv(mean) + LN2 affine + residual + relu: half-wave per node =============
__global__ __launch_bounds__(256) void simpleconv_kernel(const int* __restrict__ row_ptr,
                                                         const unsigned* __restrict__ col,
                                                         const bf16* __restrict__ Hin,
                                                         const float* __restrict__ X,
                                                         const double* __restrict__ stats,
                                                         const float* __restrict__ lnw,
                                                         const float* __restrict__ lnb,
                                                         float* __restrict__ Out) {
    int tid = threadIdx.x;
    int sl = tid & 31;
    int n = blockIdx.x * 8 + (tid >> 5);
    int c0 = sl * 4;
    int beg = row_ptr[n], end = row_ptr[n + 1];
    int deg = end - beg;
    const ushort* Hp = (const ushort*)Hin + c0;

    float acc[4] = {0.f, 0.f, 0.f, 0.f};
    for (int base = 0; base < deg; base += 32) {
        int ecnt = min(32, deg - base);
        int sv = 0;
        if (sl < ecnt) sv = (int)(col[beg + base + sl] & 0xffffu);
        int j = 0;
        for (; j + 7 < ecnt; j += 8) {
            int s[8]; uint2 h[8];
            #pragma unroll
            for (int u = 0; u < 8; ++u) s[u] = __shfl(sv, j + u, 32);
            #pragma unroll
            for (int u = 0; u < 8; ++u) h[u] = *(const uint2*)(Hp + (size_t)s[u] * DD);
            #pragma unroll
            for (int u = 0; u < 8; ++u) {
                acc[0] += bflo(h[u].x); acc[1] += bfhi(h[u].x);
                acc[2] += bflo(h[u].y); acc[3] += bfhi(h[u].y);
            }
        }
        for (; j < ecnt; ++j) {
            int s = __shfl(sv, j, 32);
            uint2 hv = *(const uint2*)(Hp + (size_t)s * DD);
            acc[0] += bflo(hv.x); acc[1] += bfhi(hv.x);
            acc[2] += bflo(hv.y); acc[3] += bfhi(hv.y);
        }
    }

    const double M = (double)NN * DD;
    double mean_d = stats[0] / M;
    double var_d = stats[1] / M - mean_d * mean_d;
    float mean2 = (float)mean_d;
    float inv2 = rsqrtf((float)var_d + EPSL);
    float rc = 1.f / (float)((deg > 0) ? deg : 1);
    float4 xr = *(const float4*)&X[(size_t)n * DD + c0];
    float4 o;
    if (deg > 0) {
        float4 lw = *(const float4*)&lnw[c0];
        float4 lb = *(const float4*)&lnb[c0];
        o.x = (acc[0] * rc - mean2) * inv2 * lw.x + lb.x;
        o.y = (acc[1] * rc - mean2) * inv2 * lw.y + lb.y;
        o.z = (acc[2] * rc - mean2) * inv2 * lw.z + lb.z;
        o.w = (acc[3] * rc - mean2) * inv2 * lw.w + lb.w;
    } else {
        o.x = o.y = o.z = o.w = 0.f;
    }
    o.x = fmaxf(o.x + xr.x, 0.f);
    o.y = fmaxf(o.y + xr.y, 0.f);
    o.z = fmaxf(o.z + xr.z, 0.f);
    o.w = fmaxf(o.w + xr.w, 0.f);
    *(float4*)&Out[(size_t)n * DD + c0] = o;
}

extern "C" void kernel_launch(void* const* d_in, const int* in_sizes, int n_in,
                              void* d_out, int out_size, void* d_ws, size_t ws_size,
                              hipStream_t stream) {
    const float* x    = (const float*)d_in[0];
    const int*   ei   = (const int*)d_in[1];
    const float* W1   = (const float*)d_in[2];
    const float* as1  = (const float*)d_in[3];
    const float* ad1  = (const float*)d_in[4];
    const float* b1   = (const float*)d_in[5];
    const float* ln1w = (const float*)d_in[6];
    const float* ln1b = (const float*)d_in[7];
    const float* W2   = (const float*)d_in[8];
    const float* as2  = (const float*)d_in[9];
    const float* ad2  = (const float*)d_in[10];
    const float* b2   = (const float*)d_in[11];
    const float* ln2w = (const float*)d_in[12];
    const float* ln2b = (const float*)d_in[13];
    float* out = (float*)d_out;

    char* p = (char*)d_ws;
    auto alloc = [&](size_t bytes) {
        void* r = (void*)p;
        p += (bytes + 255) & ~(size_t)255;
        return r;
    };
    unsigned* keys    = (unsigned*)alloc((size_t)EE * 4);
    unsigned* tmp     = (unsigned*)alloc((size_t)EE * 4);
    unsigned* col     = (unsigned*)alloc((size_t)EE * 4);
    int*      histG   = (int*)alloc((size_t)HM * 4);
    int*      offs    = (int*)alloc((size_t)HM * 4);
    int*      bstart  = (int*)alloc((size_t)(NBKT + 1) * 4);
    int*      row_ptr = (int*)alloc((size_t)(NN + 256) * 4);
    double*   stats1  = (double*)alloc(16);
    double*   stats2  = (double*)alloc(16);
    float2*   pstats  = (float2*)alloc((size_t)NN * 8);
    bf16*     bufH    = (bf16*)alloc((size_t)NN * DD * 2);   // h1, later h2 (bf16, gathered)
    float*    bufF    = (float*)alloc((size_t)NN * DD * 4);  // out1 fp32; later out2 bf16 alias
    bf16*     out2    = (bf16*)bufF;
    float*    aS1     = (float*)alloc((size_t)NN * 2 * 4);
    float*    aD1     = (float*)alloc((size_t)NN * 2 * 4);
    float*    aS2     = (float*)alloc((size_t)NN * 4);
    float*    aD2     = (float*)alloc((size_t)NN * 4);

    // ---- CSR build (bucket sort, dense writes; row_ptr fused into pass 2) ----
    pack_hist_kernel<<<NB, 256, 0, stream>>>(ei, keys, histG);
    scan_hist_kernel<<<1, 1024, 0, stream>>>(histG, offs, bstart);
    scatter_pass1_kernel<<<NB, 256, 0, stream>>>(keys, offs, tmp);
    bucket_sort_kernel<<<NBKT, 256, 0, stream>>>(tmp, bstart, col, row_ptr);

    const int GB = (NN + GROWS - 1) / GROWS;   // 782
    const int AB = NN / 8;                     // 6250 (exact)

    // layer 1: GATConv(128 -> 64, heads=2, concat); LN1+relu deferred into next gemm
    gemm_attn<2, false><<<GB, 512, 0, stream>>>(x, W1, as1, ad1,
                                                nullptr, nullptr, nullptr,
                                                bufH, aS1, aD1);
    gat_agg<2, float><<<AB, 256, 0, stream>>>(row_ptr, col, bufH, aS1, aD1, b1, bufF, pstats);
    reduce_stats_kernel<<<1, 1024, 0, stream>>>(pstats, stats1);

    // layer 2: GATConv(128 -> 128, heads=1), input = relu(ln1(out1)) fused into gemm
    gemm_attn<1, true><<<GB, 512, 0, stream>>>(bufF, W2, as2, ad2,
                                               stats1, ln1w, ln1b,
                                               bufH, aS2, aD2);
    gat_agg<1, bf16><<<AB, 256, 0, stream>>>(row_ptr, col, bufH, aS2, aD2, b2, out2, pstats);
    reduce_stats_kernel<<<1, 1024, 0, stream>>>(pstats, stats2);

    // SimpleConv mean over original edges + LN2 affine + residual + relu (fused)
    simpleconv_kernel<<<AB, 256, 0, stream>>>(row_ptr, col, out2, x,
                                              stats2, ln2w, ln2b, out);
}

// Round 11
// 296.126 us; speedup vs baseline: 1.6101x; 1.0852x over previous
//
#include <hip/hip_runtime.h>
#include <hip/hip_bf16.h>
#include <cstdint>
#include <cstddef>

#define NN 50000
#define EE 800000
#define DD 128
#define NEG 0.2f
#define EPSL 1e-5f

// bucket sort config: 196 pass-1 blocks x 4096 edges (196*4096 = 802816 >= EE)
#define NB   196
#define EPB  4096
#define NBKT 196                 // buckets = dst>>8
#define HM   (NBKT * NB)         // 38416

#define GROWS 64                 // rows per gemm block

typedef __hip_bfloat16 bf16;
typedef short short8 __attribute__((ext_vector_type(8)));
typedef float f32x4 __attribute__((ext_vector_type(4)));

__device__ inline float bflo(unsigned u) { return __uint_as_float(u << 16); }
__device__ inline float bfhi(unsigned u) { return __uint_as_float(u & 0xffff0000u); }

__device__ inline unsigned short f2bf(float f) {
    __bf16 h = (__bf16)f;
    return __builtin_bit_cast(unsigned short, h);
}
__device__ inline unsigned pack2(float a, float b) {
    return (unsigned)f2bf(a) | ((unsigned)f2bf(b) << 16);
}

__device__ inline void store4(float* Out, size_t idx, float4 v) {
    *(float4*)&Out[idx] = v;
}
__device__ inline void store4(bf16* Out, size_t idx, float4 v) {
    union { bf16 b[4]; ushort4 u; } cv;
    cv.b[0] = (bf16)v.x; cv.b[1] = (bf16)v.y; cv.b[2] = (bf16)v.z; cv.b[3] = (bf16)v.w;
    *(ushort4*)&Out[idx] = cv.u;
}

// ================= CSR build: MSD bucket sort (dense writes, no global atomics) ============

// pass A: per-block bucket histogram (dst reads only; no key materialization)
__global__ __launch_bounds__(256) void hist_kernel(const int* __restrict__ ei,
                                                   int* __restrict__ histG) {
    __shared__ int lh[NBKT];
    int tid = threadIdx.x;
    for (int t = tid; t < NBKT; t += 256) lh[t] = 0;
    __syncthreads();
    int base = blockIdx.x * EPB;
    #pragma unroll
    for (int j = 0; j < EPB / 256; ++j) {
        int i = base + j * 256 + tid;
        if (i < EE) {
            unsigned d = (unsigned)ei[EE + i];
            atomicAdd(&lh[d >> 8], 1);
        }
    }
    __syncthreads();
    for (int t = tid; t < NBKT; t += 256) histG[t * NB + blockIdx.x] = lh[t];
}

__global__ __launch_bounds__(1024) void scan_hist_kernel(const int* __restrict__ histG,
                                                         int* __restrict__ offs,
                                                         int* __restrict__ bstart) {
    __shared__ int wsum[16];
    __shared__ int carry_s;
    int tid = threadIdx.x, lane = tid & 63, wv = tid >> 6;
    if (tid == 0) carry_s = 0;
    __syncthreads();
    for (int base = 0; base < HM; base += 4096) {
        int i4 = base + tid * 4;
        int4 v = make_int4(0, 0, 0, 0);
        if (i4 + 3 < HM) v = *(const int4*)&histG[i4];
        else {
            if (i4 + 0 < HM) v.x = histG[i4 + 0];
            if (i4 + 1 < HM) v.y = histG[i4 + 1];
            if (i4 + 2 < HM) v.z = histG[i4 + 2];
            if (i4 + 3 < HM) v.w = histG[i4 + 3];
        }
        int tsum = v.x + v.y + v.z + v.w;
        int x = tsum;
        for (int off = 1; off < 64; off <<= 1) {
            int t = __shfl_up(x, off);
            if (lane >= off) x += t;
        }
        if (lane == 63) wsum[wv] = x;
        __syncthreads();
        if (wv == 0) {
            int s = (lane < 16) ? wsum[lane] : 0;
            for (int off = 1; off < 16; off <<= 1) {
                int t = __shfl_up(s, off);
                if (lane >= off) s += t;
            }
            if (lane < 16) wsum[lane] = s;
        }
        __syncthreads();
        int waveoff = (wv == 0) ? 0 : wsum[wv - 1];
        int carry = carry_s;
        int o0 = carry + waveoff + x - tsum;
        int o1 = o0 + v.x, o2 = o1 + v.y, o3 = o2 + v.z;
        if (i4 + 3 < HM) *(int4*)&offs[i4] = make_int4(o0, o1, o2, o3);
        else {
            if (i4 + 0 < HM) offs[i4 + 0] = o0;
            if (i4 + 1 < HM) offs[i4 + 1] = o1;
            if (i4 + 2 < HM) offs[i4 + 2] = o2;
            if (i4 + 3 < HM) offs[i4 + 3] = o3;
        }
        if (i4 < HM && (i4 % NB) == 0) bstart[i4 / NB] = o0;  // NB % 4 == 0 -> boundary at .x
        __syncthreads();
        if (tid == 0) carry_s += wsum[15];
        __syncthreads();
    }
    if (tid == 0) bstart[NBKT] = carry_s;   // == EE
}

// pass 1 scatter: re-read ei, pack key, write per-(bucket,block) contiguous regions
__global__ __launch_bounds__(256) void scatter_pass1_kernel(const int* __restrict__ ei,
                                                            const int* __restrict__ offs,
                                                            unsigned* __restrict__ tmp) {
    __shared__ int lofs[NBKT];
    int tid = threadIdx.x;
    for (int t = tid; t < NBKT; t += 256) lofs[t] = offs[t * NB + blockIdx.x];
    __syncthreads();
    int base = blockIdx.x * EPB;
    #pragma unroll
    for (int j = 0; j < EPB / 256; ++j) {
        int i = base + j * 256 + tid;
        if (i < EE) {
            unsigned s = (unsigned)ei[i];
            unsigned d = (unsigned)ei[EE + i];
            unsigned key = (d << 16) | s;
            int pos = atomicAdd(&lofs[d >> 8], 1);
            tmp[pos] = key;
        }
    }
}

// pass 2: counting sort by dst low byte; ALSO emits row_ptr (the scan IS row_ptr)
__global__ __launch_bounds__(256) void bucket_sort_kernel(const unsigned* __restrict__ tmp,
                                                          const int* __restrict__ bstart,
                                                          unsigned* __restrict__ col,
                                                          int* __restrict__ row_ptr) {
    __shared__ int cnt[256];
    __shared__ int cpos[256];
    __shared__ int wtot[4];
    int tid = threadIdx.x, lane = tid & 63, wv = tid >> 6;
    int s0 = bstart[blockIdx.x], s1 = bstart[blockIdx.x + 1];
    cnt[tid] = 0;
    __syncthreads();
    for (int i = s0 + tid; i < s1; i += 256)
        atomicAdd(&cnt[(tmp[i] >> 16) & 0xFF], 1);
    __syncthreads();
    int v = cnt[tid];
    int x = v;
    for (int off = 1; off < 64; off <<= 1) {
        int t = __shfl_up(x, off);
        if (lane >= off) x += t;
    }
    if (lane == 63) wtot[wv] = x;
    __syncthreads();
    int add = 0;
    for (int k = 0; k < wv; ++k) add += wtot[k];
    int start = s0 + add + x - v;
    cpos[tid] = start;
    int d = blockIdx.x * 256 + tid;
    if (d <= NN) row_ptr[d] = start;
    __syncthreads();
    for (int i = s0 + tid; i < s1; i += 256) {
        unsigned key = tmp[i];
        int pos = atomicAdd(&cpos[(key >> 16) & 0xFF], 1);
        col[pos] = key;
    }
}

// ================= MFMA GEMM (+optional fused LN1+relu) + attention dots ===================
// 512 threads = 8 waves; 64 rows/block. Wave w: rows (w&3)*16..+16, cols (w>>2)*64..+64.
// mfma_f32_16x16x32_bf16 layouts (HW-verified): A[m=lane&15][k=quad*8+j],
// B[n=lane&15][k=quad*8+j], C/D col=lane&15, row=quad*4+reg.
// LDS row strides: 136 shorts = 272 B = 17*16 -> b64/b128 accesses aligned.
template <int H, bool LN>
__global__ __launch_bounds__(512) void gemm_attn(const float* __restrict__ X,
                                                 const float* __restrict__ W,
                                                 const float* __restrict__ att_s,
                                                 const float* __restrict__ att_d,
                                                 const double* __restrict__ stats,
                                                 const float* __restrict__ lnw,
                                                 const float* __restrict__ lnb,
                                                 bf16* __restrict__ Hout,
                                                 float* __restrict__ a_src,
                                                 float* __restrict__ a_dst) {
    __shared__ __align__(16) char lds[(128 * 136 + 64 * 136) * 2 + 2048];  // 54272 B
    unsigned short* Bt = (unsigned short*)lds;                    // [128][136] (W^T)
    unsigned short* As = (unsigned short*)(lds + 128 * 136 * 2);  // [64][136]
    float* Cs = (float*)lds;                                      // [64][132] (reuse)
    float* psum = (float*)(lds + (128 * 136 + 64 * 136) * 2);     // [256] (H==1 combine)

    int tid = threadIdx.x;
    int row0 = blockIdx.x * GROWS;

    // ---- stage W -> Bt transposed: 4 k-consecutive bf16 per b64 write ----
    {
        int c = tid & 127, kg = tid >> 7;   // kg in 0..3
        #pragma unroll 2
        for (int i = 0; i < 8; ++i) {
            int k0 = i * 16 + kg * 4;
            float wa = W[(size_t)(k0 + 0) * DD + c];
            float wb = W[(size_t)(k0 + 1) * DD + c];
            float wcv = W[(size_t)(k0 + 2) * DD + c];
            float wdv = W[(size_t)(k0 + 3) * DD + c];
            uint2 pk = make_uint2(pack2(wa, wb), pack2(wcv, wdv));
            *(uint2*)&Bt[c * 136 + k0] = pk;
        }
    }
    // ---- stage X (+LN+relu) -> As: float4 loads, b64 LDS writes ----
    {
        int sub = tid & 31, rq = tid >> 5;  // col-group 0..31, row-slot 0..15
        int c4 = sub * 4;
        float mean = 0.f, inv = 1.f;
        float4 lw4 = make_float4(1.f, 1.f, 1.f, 1.f), lb4 = make_float4(0.f, 0.f, 0.f, 0.f);
        if (LN) {
            const double M = (double)NN * DD;
            double mean_d = stats[0] / M;
            double var_d = stats[1] / M - mean_d * mean_d;
            mean = (float)mean_d;
            inv = rsqrtf((float)var_d + EPSL);
            lw4 = *(const float4*)&lnw[c4];
            lb4 = *(const float4*)&lnb[c4];
        }
        #pragma unroll
        for (int i = 0; i < 4; ++i) {
            int r = i * 16 + rq;
            int row = row0 + r;
            float4 xv = make_float4(0.f, 0.f, 0.f, 0.f);
            if (row < NN) xv = *(const float4*)&X[(size_t)row * DD + c4];
            if (LN) {
                xv.x = fmaxf((xv.x - mean) * inv * lw4.x + lb4.x, 0.f);
                xv.y = fmaxf((xv.y - mean) * inv * lw4.y + lb4.y, 0.f);
                xv.z = fmaxf((xv.z - mean) * inv * lw4.z + lb4.z, 0.f);
                xv.w = fmaxf((xv.w - mean) * inv * lw4.w + lb4.w, 0.f);
            }
            uint2 pk = make_uint2(pack2(xv.x, xv.y), pack2(xv.z, xv.w));
            *(uint2*)&As[r * 136 + c4] = pk;
        }
    }
    __syncthreads();

    int lane = tid & 63, w = tid >> 6;    // 8 waves
    int rg = w & 3, cg = w >> 2;          // row-group, col-group
    int l15 = lane & 15, quad = lane >> 4;
    f32x4 acc[4];
    #pragma unroll
    for (int t = 0; t < 4; ++t) acc[t] = 0.f;
    const unsigned short* Arow = As + (rg * 16 + l15) * 136 + quad * 8;
    const unsigned short* Brow = Bt + l15 * 136 + quad * 8;
    #pragma unroll
    for (int ks = 0; ks < 4; ++ks) {
        short8 a = *(const short8*)(Arow + ks * 32);
        #pragma unroll
        for (int tt = 0; tt < 4; ++tt) {
            short8 b = *(const short8*)(Brow + (cg * 4 + tt) * 16 * 136 + ks * 32);
            acc[tt] = __builtin_amdgcn_mfma_f32_16x16x32_bf16(a, b, acc[tt], 0, 0, 0);
        }
    }
    __syncthreads();   // all waves done reading Bt/As; Cs may overwrite

    #pragma unroll
    for (int tt = 0; tt < 4; ++tt)
        #pragma unroll
        for (int r = 0; r < 4; ++r)
            Cs[(rg * 16 + quad * 4 + r) * 132 + (cg * 4 + tt) * 16 + l15] = acc[tt][r];

    // attention dots: wave covers cols (cg*4+tt)*16+l15; for H=2 head == cg exactly
    float ds[4] = {0.f, 0.f, 0.f, 0.f}, dd[4] = {0.f, 0.f, 0.f, 0.f};
    #pragma unroll
    for (int tt = 0; tt < 4; ++tt) {
        int cc = (cg * 4 + tt) * 16 + l15;
        float as_ = att_s[cc], ad_ = att_d[cc];
        #pragma unroll
        for (int r = 0; r < 4; ++r) {
            ds[r] = fmaf(acc[tt][r], as_, ds[r]);
            dd[r] = fmaf(acc[tt][r], ad_, dd[r]);
        }
    }
    #pragma unroll
    for (int off = 1; off < 16; off <<= 1) {
        #pragma unroll
        for (int r = 0; r < 4; ++r) {
            ds[r] += __shfl_xor(ds[r], off);
            dd[r] += __shfl_xor(dd[r], off);
        }
    }
    if (l15 == 0) {
        #pragma unroll
        for (int r = 0; r < 4; ++r) {
            int rr = rg * 16 + quad * 4 + r;
            int row = row0 + rr;
            if (H == 2) {
                if (row < NN) {
                    a_src[row * 2 + cg] = ds[r];
                    a_dst[row * 2 + cg] = dd[r];
                }
            } else {
                psum[cg * 64 + rr] = ds[r];
                psum[128 + cg * 64 + rr] = dd[r];
            }
        }
    }
    __syncthreads();

    if (H == 1 && tid < 64) {
        int row = row0 + tid;
        if (row < NN) {
            a_src[row] = psum[tid] + psum[64 + tid];
            a_dst[row] = psum[128 + tid] + psum[192 + tid];
        }
    }

    // ---- coalesced readout: float4 LDS reads, ushort4 global stores ----
    {
        int sub = tid & 31, rq = tid >> 5;
        int c4 = sub * 4;
        unsigned short* Hp = (unsigned short*)Hout;
        #pragma unroll
        for (int i = 0; i < 4; ++i) {
            int r = i * 16 + rq;
            int row = row0 + r;
            if (row < NN) {
                float4 cv = *(const float4*)&Cs[r * 132 + c4];
                ushort4 pk;
                pk.x = f2bf(cv.x); pk.y = f2bf(cv.y);
                pk.z = f2bf(cv.z); pk.w = f2bf(cv.w);
                *(ushort4*)&Hp[(size_t)row * DD + c4] = pk;
            }
        }
    }
}

// ============ GAT softmax + aggregate: HALF-WAVE PER NODE, shuffle broadcast ==============
template <int H, typename OT>
__global__ __launch_bounds__(256) void gat_agg(const int* __restrict__ row_ptr,
                                               const unsigned* __restrict__ col,
                                               const bf16* __restrict__ Hin,
                                               const float* __restrict__ a_src,
                                               const float* __restrict__ a_dst,
                                               const float* __restrict__ bias,
                                               OT* __restrict__ Out,
                                               float2* __restrict__ pstats) {
    int tid = threadIdx.x;
    int sl = tid & 31;
    int n = blockIdx.x * 8 + (tid >> 5);
    int c0 = sl * 4;
    const int head4 = (H == 2) ? (sl >> 4) : 0;

    int beg = row_ptr[n], end = row_ptr[n + 1];
    int deg = end - beg;

    float ad0 = a_dst[n * H + 0];
    float ad1 = (H == 2) ? a_dst[n * H + 1] : 0.f;
    const ushort* Hp = (const ushort*)Hin + c0;

    float acc[4] = {0.f, 0.f, 0.f, 0.f};
    float dl0 = 0.f, dl1 = 0.f;

    for (int base = 0; base < deg; base += 32) {
        int ecnt = min(32, deg - base);
        int sv = 0; float w0v = 0.f, w1v = 0.f;
        if (sl < ecnt) {
            sv = (int)(col[beg + base + sl] & 0xffffu);
            if (H == 2) {
                float2 av = *(const float2*)&a_src[sv * 2];
                float e0 = av.x + ad0; e0 = (e0 > 0.f) ? e0 : NEG * e0;
                float e1 = av.y + ad1; e1 = (e1 > 0.f) ? e1 : NEG * e1;
                w0v = __expf(e0); w1v = __expf(e1);
                dl0 += w0v; dl1 += w1v;
            } else {
                float e0 = a_src[sv] + ad0; e0 = (e0 > 0.f) ? e0 : NEG * e0;
                w0v = __expf(e0);
                dl0 += w0v;
            }
        }
        int j = 0;
        for (; j + 7 < ecnt; j += 8) {
            int s[8]; float ww[8];
            uint2 h[8];
            #pragma unroll
            for (int u = 0; u < 8; ++u) {
                s[u] = __shfl(sv, j + u, 32);
                if (H == 2) {
                    float a0 = __shfl(w0v, j + u, 32), b0 = __shfl(w1v, j + u, 32);
                    ww[u] = head4 ? b0 : a0;
                } else {
                    ww[u] = __shfl(w0v, j + u, 32);
                }
            }
            #pragma unroll
            for (int u = 0; u < 8; ++u) h[u] = *(const uint2*)(Hp + (size_t)s[u] * DD);
            #pragma unroll
            for (int u = 0; u < 8; ++u) {
                acc[0] = fmaf(ww[u], bflo(h[u].x), acc[0]);
                acc[1] = fmaf(ww[u], bfhi(h[u].x), acc[1]);
                acc[2] = fmaf(ww[u], bflo(h[u].y), acc[2]);
                acc[3] = fmaf(ww[u], bfhi(h[u].y), acc[3]);
            }
        }
        for (; j < ecnt; ++j) {
            int s = __shfl(sv, j, 32);
            float w;
            if (H == 2) {
                float a0 = __shfl(w0v, j, 32), b0 = __shfl(w1v, j, 32);
                w = head4 ? b0 : a0;
            } else {
                w = __shfl(w0v, j, 32);
            }
            uint2 hv = *(const uint2*)(Hp + (size_t)s * DD);
            acc[0] = fmaf(w, bflo(hv.x), acc[0]); acc[1] = fmaf(w, bfhi(hv.x), acc[1]);
            acc[2] = fmaf(w, bflo(hv.y), acc[2]); acc[3] = fmaf(w, bfhi(hv.y), acc[3]);
        }
    }

    #pragma unroll
    for (int off = 1; off < 32; off <<= 1) {
        dl0 += __shfl_xor(dl0, off);
        if (H == 2) dl1 += __shfl_xor(dl1, off);
    }

    // implicit self-loop
    float e0 = a_src[n * H + 0] + ad0; e0 = (e0 > 0.f) ? e0 : NEG * e0;
    float ws0 = __expf(e0);
    float ws1 = 0.f;
    if (H == 2) {
        float e1 = a_src[n * H + 1] + ad1; e1 = (e1 > 0.f) ? e1 : NEG * e1;
        ws1 = __expf(e1);
    }
    float den = (H == 2 && head4) ? (dl1 + ws1) : (dl0 + ws0);
    float wself = (H == 2 && head4) ? ws1 : ws0;
    float rinv = 1.f / (den + 1e-16f);
    uint2 hs = *(const uint2*)(Hp + (size_t)n * DD);
    float4 bi = *(const float4*)&bias[c0];
    float4 o;
    o.x = fmaf(wself, bflo(hs.x), acc[0]) * rinv + bi.x;
    o.y = fmaf(wself, bfhi(hs.x), acc[1]) * rinv + bi.y;
    o.z = fmaf(wself, bflo(hs.y), acc[2]) * rinv + bi.z;
    o.w = fmaf(wself, bfhi(hs.y), acc[3]) * rinv + bi.w;
    store4(Out, (size_t)n * DD + c0, o);

    float t1 = o.x + o.y + o.z + o.w;
    float t2 = o.x * o.x + o.y * o.y + o.z * o.z + o.w * o.w;
    #pragma unroll
    for (int off = 1; off < 32; off <<= 1) {
        t1 += __shfl_xor(t1, off);
        t2 += __shfl_xor(t2, off);
    }
    if (sl == 0) pstats[n] = make_float2(t1, t2);
}

// ---------------- deterministic single-block reduce of per-node LN partials ----------------
__global__ __launch_bounds__(1024) void reduce_stats_kernel(const float2* __restrict__ pstats,
                                                            double* __restrict__ stats) {
    int tid = threadIdx.x, lane = tid & 63, wv = tid >> 6;
    double s1 = 0.0, s2 = 0.0;
    for (int i = tid; i < NN; i += 1024) {
        float2 v = pstats[i];
        s1 += (double)v.x; s2 += (double)v.y;
    }
    for (int off = 32; off; off >>= 1) {
        s1 += __shfl_xor(s1, off);
        s2 += __shfl_xor(s2, off);
    }
    __shared__ double w1[16], w2[16];
    if (lane == 0) { w1[wv] = s1; w2[wv] = s2; }
    __syncthreads();
    if (tid == 0) {
        double a = 0.0, b = 0.0;
        for (int i = 0; i < 16; ++i) { a += w1[i]; b += w2[i]; }
        stats[0] = a; stats[1] = b;
    }
}

// ======== SimpleConv(mean) + LN2 affine + residual + relu: half-wave per node =============
__global__ __launch_bounds__(256) void simpleconv_kernel(const int* __restrict__ row_ptr,
                                                         const unsigned* __restrict__ col,
                                                         const bf16* __restrict__ Hin,
                                                         const float* __restrict__ X,
                                                         const double* __restrict__ stats,
                                                         const float* __restrict__ lnw,
                                                         const float* __restrict__ lnb,
                                                         float* __restrict__ Out) {
    int tid = threadIdx.x;
    int sl = tid & 31;
    int n = blockIdx.x * 8 + (tid >> 5);
    int c0 = sl * 4;
    int beg = row_ptr[n], end = row_ptr[n + 1];
    int deg = end - beg;
    const ushort* Hp = (const ushort*)Hin + c0;

    float acc[4] = {0.f, 0.f, 0.f, 0.f};
    for (int base = 0; base < deg; base += 32) {
        int ecnt = min(32, deg - base);
        int sv = 0;
        if (sl < ecnt) sv = (int)(col[beg + base + sl] & 0xffffu);
        int j = 0;
        for (; j + 7 < ecnt; j += 8) {
            int s[8]; uint2 h[8];
            #pragma unroll
            for (int u = 0; u < 8; ++u) s[u] = __shfl(sv, j + u, 32);
            #pragma unroll
            for (int u = 0; u < 8; ++u) h[u] = *(const uint2*)(Hp + (size_t)s[u] * DD);
            #pragma unroll
            for (int u = 0; u < 8; ++u) {
                acc[0] += bflo(h[u].x); acc[1] += bfhi(h[u].x);
                acc[2] += bflo(h[u].y); acc[3] += bfhi(h[u].y);
            }
        }
        for (; j < ecnt; ++j) {
            int s = __shfl(sv, j, 32);
            uint2 hv = *(const uint2*)(Hp + (size_t)s * DD);
            acc[0] += bflo(hv.x); acc[1] += bfhi(hv.x);
            acc[2] += bflo(hv.y); acc[3] += bfhi(hv.y);
        }
    }

    const double M = (double)NN * DD;
    double mean_d = stats[0] / M;
    double var_d = stats[1] / M - mean_d * mean_d;
    float mean2 = (float)mean_d;
    float inv2 = rsqrtf((float)var_d + EPSL);
    float rc = 1.f / (float)((deg > 0) ? deg : 1);
    float4 xr = *(const float4*)&X[(size_t)n * DD + c0];
    float4 o;
    if (deg > 0) {
        float4 lw = *(const float4*)&lnw[c0];
        float4 lb = *(const float4*)&lnb[c0];
        o.x = (acc[0] * rc - mean2) * inv2 * lw.x + lb.x;
        o.y = (acc[1] * rc - mean2) * inv2 * lw.y + lb.y;
        o.z = (acc[2] * rc - mean2) * inv2 * lw.z + lb.z;
        o.w = (acc[3] * rc - mean2) * inv2 * lw.w + lb.w;
    } else {
        o.x = o.y = o.z = o.w = 0.f;
    }
    o.x = fmaxf(o.x + xr.x, 0.f);
    o.y = fmaxf(o.y + xr.y, 0.f);
    o.z = fmaxf(o.z + xr.z, 0.f);
    o.w = fmaxf(o.w + xr.w, 0.f);
    *(float4*)&Out[(size_t)n * DD + c0] = o;
}

extern "C" void kernel_launch(void* const* d_in, const int* in_sizes, int n_in,
                              void* d_out, int out_size, void* d_ws, size_t ws_size,
                              hipStream_t stream) {
    const float* x    = (const float*)d_in[0];
    const int*   ei   = (const int*)d_in[1];
    const float* W1   = (const float*)d_in[2];
    const float* as1  = (const float*)d_in[3];
    const float* ad1  = (const float*)d_in[4];
    const float* b1   = (const float*)d_in[5];
    const float* ln1w = (const float*)d_in[6];
    const float* ln1b = (const float*)d_in[7];
    const float* W2   = (const float*)d_in[8];
    const float* as2  = (const float*)d_in[9];
    const float* ad2  = (const float*)d_in[10];
    const float* b2   = (const float*)d_in[11];
    const float* ln2w = (const float*)d_in[12];
    const float* ln2b = (const float*)d_in[13];
    float* out = (float*)d_out;

    char* p = (char*)d_ws;
    auto alloc = [&](size_t bytes) {
        void* r = (void*)p;
        p += (bytes + 255) & ~(size_t)255;
        return r;
    };
    unsigned* tmp     = (unsigned*)alloc((size_t)EE * 4);
    unsigned* col     = (unsigned*)alloc((size_t)EE * 4);
    int*      histG   = (int*)alloc((size_t)HM * 4);
    int*      offs    = (int*)alloc((size_t)HM * 4);
    int*      bstart  = (int*)alloc((size_t)(NBKT + 1) * 4);
    int*      row_ptr = (int*)alloc((size_t)(NN + 256) * 4);
    double*   stats1  = (double*)alloc(16);
    double*   stats2  = (double*)alloc(16);
    float2*   pstats  = (float2*)alloc((size_t)NN * 8);
    bf16*     bufH    = (bf16*)alloc((size_t)NN * DD * 2);   // h1, later h2 (bf16, gathered)
    float*    bufF    = (float*)alloc((size_t)NN * DD * 4);  // out1 fp32; later out2 bf16 alias
    bf16*     out2    = (bf16*)bufF;
    float*    aS1     = (float*)alloc((size_t)NN * 2 * 4);
    float*    aD1     = (float*)alloc((size_t)NN * 2 * 4);
    float*    aS2     = (float*)alloc((size_t)NN * 4);
    float*    aD2     = (float*)alloc((size_t)NN * 4);

    // ---- CSR build (bucket sort, dense writes; no key buffer; row_ptr fused) ----
    hist_kernel<<<NB, 256, 0, stream>>>(ei, histG);
    scan_hist_kernel<<<1, 1024, 0, stream>>>(histG, offs, bstart);
    scatter_pass1_kernel<<<NB, 256, 0, stream>>>(ei, offs, tmp);
    bucket_sort_kernel<<<NBKT, 256, 0, stream>>>(tmp, bstart, col, row_ptr);

    const int GB = (NN + GROWS - 1) / GROWS;   // 782
    const int AB = NN / 8;                     // 6250 (exact)

    // layer 1: GATConv(128 -> 64, heads=2, concat); LN1+relu deferred into next gemm
    gemm_attn<2, false><<<GB, 512, 0, stream>>>(x, W1, as1, ad1,
                                                nullptr, nullptr, nullptr,
                                                bufH, aS1, aD1);
    gat_agg<2, float><<<AB, 256, 0, stream>>>(row_ptr, col, bufH, aS1, aD1, b1, bufF, pstats);
    reduce_stats_kernel<<<1, 1024, 0, stream>>>(pstats, stats1);

    // layer 2: GATConv(128 -> 128, heads=1), input = relu(ln1(out1)) fused into gemm
    gemm_attn<1, true><<<GB, 512, 0, stream>>>(bufF, W2, as2, ad2,
                                               stats1, ln1w, ln1b,
                                               bufH, aS2, aD2);
    gat_agg<1, bf16><<<AB, 256, 0, stream>>>(row_ptr, col, bufH, aS2, aD2, b2, out2, pstats);
    reduce_stats_kernel<<<1, 1024, 0, stream>>>(pstats, stats2);

    // SimpleConv mean over original edges + LN2 affine + residual + relu (fused)
    simpleconv_kernel<<<AB, 256, 0, stream>>>(row_ptr, col, out2, x,
                                              stats2, ln2w, ln2b, out);
}

// Round 12
// 274.746 us; speedup vs baseline: 1.7354x; 1.0778x over previous
//
#include <hip/hip_runtime.h>
#include <hip/hip_bf16.h>
#include <cstdint>
#include <cstddef>

#define NN 50000
#define EE 800000
#define DD 128
#define NEG 0.2f
#define EPSL 1e-5f

// bucket sort config: 196 pass-1 blocks x 4096 edges (196*4096 = 802816 >= EE)
#define NB   196
#define EPB  4096
#define NBKT 196                 // buckets = dst>>8
#define HM   (NBKT * NB)         // 38416

#define GROWS 64                 // rows per gemm block
#define AB    (NN / 8)           // gat_agg blocks (8 nodes each) = 6250

typedef __hip_bfloat16 bf16;
typedef short short8 __attribute__((ext_vector_type(8)));
typedef float f32x4 __attribute__((ext_vector_type(4)));

__device__ inline float bflo(unsigned u) { return __uint_as_float(u << 16); }
__device__ inline float bfhi(unsigned u) { return __uint_as_float(u & 0xffff0000u); }
__device__ inline float bf2f(unsigned short u) { return __uint_as_float((unsigned)u << 16); }

__device__ inline unsigned short f2bf(float f) {
    __bf16 h = (__bf16)f;
    return __builtin_bit_cast(unsigned short, h);
}
__device__ inline unsigned pack2(float a, float b) {
    return (unsigned)f2bf(a) | ((unsigned)f2bf(b) << 16);
}

__device__ inline void store4(float* Out, size_t idx, float4 v) {
    *(float4*)&Out[idx] = v;
}
__device__ inline void store4(bf16* Out, size_t idx, float4 v) {
    union { bf16 b[4]; ushort4 u; } cv;
    cv.b[0] = (bf16)v.x; cv.b[1] = (bf16)v.y; cv.b[2] = (bf16)v.z; cv.b[3] = (bf16)v.w;
    *(ushort4*)&Out[idx] = cv.u;
}

// ================= CSR build: MSD bucket sort (dense writes, no global atomics) ============

// pass A: per-block bucket histogram (int4-vectorized dst reads)
__global__ __launch_bounds__(256) void hist_kernel(const int* __restrict__ ei,
                                                   int* __restrict__ histG) {
    __shared__ int lh[NBKT];
    int tid = threadIdx.x;
    for (int t = tid; t < NBKT; t += 256) lh[t] = 0;
    __syncthreads();
    int base = blockIdx.x * EPB;
    #pragma unroll
    for (int j = 0; j < EPB / 1024; ++j) {
        int i4 = base + (j * 256 + tid) * 4;
        if (i4 < EE) {   // EE % 4 == 0, i4 % 4 == 0 -> full int4 in-bounds
            int4 d4 = *(const int4*)&ei[EE + i4];
            atomicAdd(&lh[(unsigned)d4.x >> 8], 1);
            atomicAdd(&lh[(unsigned)d4.y >> 8], 1);
            atomicAdd(&lh[(unsigned)d4.z >> 8], 1);
            atomicAdd(&lh[(unsigned)d4.w >> 8], 1);
        }
    }
    __syncthreads();
    for (int t = tid; t < NBKT; t += 256) histG[t * NB + blockIdx.x] = lh[t];
}

__global__ __launch_bounds__(1024) void scan_hist_kernel(const int* __restrict__ histG,
                                                         int* __restrict__ offs,
                                                         int* __restrict__ bstart) {
    __shared__ int wsum[16];
    __shared__ int carry_s;
    int tid = threadIdx.x, lane = tid & 63, wv = tid >> 6;
    if (tid == 0) carry_s = 0;
    __syncthreads();
    for (int base = 0; base < HM; base += 4096) {
        int i4 = base + tid * 4;
        int4 v = make_int4(0, 0, 0, 0);
        if (i4 + 3 < HM) v = *(const int4*)&histG[i4];
        else {
            if (i4 + 0 < HM) v.x = histG[i4 + 0];
            if (i4 + 1 < HM) v.y = histG[i4 + 1];
            if (i4 + 2 < HM) v.z = histG[i4 + 2];
            if (i4 + 3 < HM) v.w = histG[i4 + 3];
        }
        int tsum = v.x + v.y + v.z + v.w;
        int x = tsum;
        for (int off = 1; off < 64; off <<= 1) {
            int t = __shfl_up(x, off);
            if (lane >= off) x += t;
        }
        if (lane == 63) wsum[wv] = x;
        __syncthreads();
        if (wv == 0) {
            int s = (lane < 16) ? wsum[lane] : 0;
            for (int off = 1; off < 16; off <<= 1) {
                int t = __shfl_up(s, off);
                if (lane >= off) s += t;
            }
            if (lane < 16) wsum[lane] = s;
        }
        __syncthreads();
        int waveoff = (wv == 0) ? 0 : wsum[wv - 1];
        int carry = carry_s;
        int o0 = carry + waveoff + x - tsum;
        int o1 = o0 + v.x, o2 = o1 + v.y, o3 = o2 + v.z;
        if (i4 + 3 < HM) *(int4*)&offs[i4] = make_int4(o0, o1, o2, o3);
        else {
            if (i4 + 0 < HM) offs[i4 + 0] = o0;
            if (i4 + 1 < HM) offs[i4 + 1] = o1;
            if (i4 + 2 < HM) offs[i4 + 2] = o2;
            if (i4 + 3 < HM) offs[i4 + 3] = o3;
        }
        if (i4 < HM && (i4 % NB) == 0) bstart[i4 / NB] = o0;  // NB % 4 == 0
        __syncthreads();
        if (tid == 0) carry_s += wsum[15];
        __syncthreads();
    }
    if (tid == 0) bstart[NBKT] = carry_s;   // == EE
}

// pass 1 scatter: int4 reads of src/dst, pack key, per-(bucket,block) contiguous regions
__global__ __launch_bounds__(256) void scatter_pass1_kernel(const int* __restrict__ ei,
                                                            const int* __restrict__ offs,
                                                            unsigned* __restrict__ tmp) {
    __shared__ int lofs[NBKT];
    int tid = threadIdx.x;
    for (int t = tid; t < NBKT; t += 256) lofs[t] = offs[t * NB + blockIdx.x];
    __syncthreads();
    int base = blockIdx.x * EPB;
    #pragma unroll
    for (int j = 0; j < EPB / 1024; ++j) {
        int i4 = base + (j * 256 + tid) * 4;
        if (i4 < EE) {
            int4 s4 = *(const int4*)&ei[i4];
            int4 d4 = *(const int4*)&ei[EE + i4];
            unsigned k0 = ((unsigned)d4.x << 16) | (unsigned)s4.x;
            unsigned k1 = ((unsigned)d4.y << 16) | (unsigned)s4.y;
            unsigned k2 = ((unsigned)d4.z << 16) | (unsigned)s4.z;
            unsigned k3 = ((unsigned)d4.w << 16) | (unsigned)s4.w;
            tmp[atomicAdd(&lofs[(unsigned)d4.x >> 8], 1)] = k0;
            tmp[atomicAdd(&lofs[(unsigned)d4.y >> 8], 1)] = k1;
            tmp[atomicAdd(&lofs[(unsigned)d4.z >> 8], 1)] = k2;
            tmp[atomicAdd(&lofs[(unsigned)d4.w >> 8], 1)] = k3;
        }
    }
}

// pass 2: counting sort by dst low byte; ALSO emits row_ptr (the scan IS row_ptr)
__global__ __launch_bounds__(256) void bucket_sort_kernel(const unsigned* __restrict__ tmp,
                                                          const int* __restrict__ bstart,
                                                          unsigned* __restrict__ col,
                                                          int* __restrict__ row_ptr) {
    __shared__ int cnt[256];
    __shared__ int cpos[256];
    __shared__ int wtot[4];
    int tid = threadIdx.x, lane = tid & 63, wv = tid >> 6;
    int s0 = bstart[blockIdx.x], s1 = bstart[blockIdx.x + 1];
    cnt[tid] = 0;
    __syncthreads();
    for (int i = s0 + tid; i < s1; i += 256)
        atomicAdd(&cnt[(tmp[i] >> 16) & 0xFF], 1);
    __syncthreads();
    int v = cnt[tid];
    int x = v;
    for (int off = 1; off < 64; off <<= 1) {
        int t = __shfl_up(x, off);
        if (lane >= off) x += t;
    }
    if (lane == 63) wtot[wv] = x;
    __syncthreads();
    int add = 0;
    for (int k = 0; k < wv; ++k) add += wtot[k];
    int start = s0 + add + x - v;
    cpos[tid] = start;
    int d = blockIdx.x * 256 + tid;
    if (d <= NN) row_ptr[d] = start;
    __syncthreads();
    for (int i = s0 + tid; i < s1; i += 256) {
        unsigned key = tmp[i];
        int pos = atomicAdd(&cpos[(key >> 16) & 0xFF], 1);
        col[pos] = key;
    }
}

// ================= MFMA GEMM (+optional fused LN1+relu) + attention dots ===================
// 512 threads = 8 waves; 64 rows/block. Wave w: rows (w&3)*16..+16, cols (w>>2)*64..+64.
// mfma_f32_16x16x32_bf16 layouts (HW-verified): A[m=lane&15][k=quad*8+j],
// B[n=lane&15][k=quad*8+j], C/D col=lane&15, row=quad*4+reg.
template <int H, bool LN, typename XT>
__global__ __launch_bounds__(512) void gemm_attn(const XT* __restrict__ X,
                                                 const float* __restrict__ W,
                                                 const float* __restrict__ att_s,
                                                 const float* __restrict__ att_d,
                                                 const double* __restrict__ stats,
                                                 const float* __restrict__ lnw,
                                                 const float* __restrict__ lnb,
                                                 bf16* __restrict__ Hout,
                                                 float* __restrict__ a_src,
                                                 float* __restrict__ a_dst) {
    __shared__ __align__(16) char lds[(128 * 136 + 64 * 136) * 2 + 2048];  // 54272 B
    unsigned short* Bt = (unsigned short*)lds;                    // [128][136] (W^T)
    unsigned short* As = (unsigned short*)(lds + 128 * 136 * 2);  // [64][136]
    float* Cs = (float*)lds;                                      // [64][132] (reuse)
    float* psum = (float*)(lds + (128 * 136 + 64 * 136) * 2);     // [256] (H==1 combine)

    int tid = threadIdx.x;
    int row0 = blockIdx.x * GROWS;

    // ---- stage W -> Bt transposed: 4 k-consecutive bf16 per b64 write ----
    {
        int c = tid & 127, kg = tid >> 7;   // kg in 0..3
        #pragma unroll 2
        for (int i = 0; i < 8; ++i) {
            int k0 = i * 16 + kg * 4;
            float wa = W[(size_t)(k0 + 0) * DD + c];
            float wb = W[(size_t)(k0 + 1) * DD + c];
            float wcv = W[(size_t)(k0 + 2) * DD + c];
            float wdv = W[(size_t)(k0 + 3) * DD + c];
            uint2 pk = make_uint2(pack2(wa, wb), pack2(wcv, wdv));
            *(uint2*)&Bt[c * 136 + k0] = pk;
        }
    }
    // ---- stage X (+LN+relu) -> As: vector loads, b64 LDS writes ----
    {
        int sub = tid & 31, rq = tid >> 5;  // col-group 0..31, row-slot 0..15
        int c4 = sub * 4;
        float mean = 0.f, inv = 1.f;
        float4 lw4 = make_float4(1.f, 1.f, 1.f, 1.f), lb4 = make_float4(0.f, 0.f, 0.f, 0.f);
        if (LN) {
            const double M = (double)NN * DD;
            double mean_d = stats[0] / M;
            double var_d = stats[1] / M - mean_d * mean_d;
            mean = (float)mean_d;
            inv = rsqrtf((float)var_d + EPSL);
            lw4 = *(const float4*)&lnw[c4];
            lb4 = *(const float4*)&lnb[c4];
        }
        #pragma unroll
        for (int i = 0; i < 4; ++i) {
            int r = i * 16 + rq;
            int row = row0 + r;
            float4 xv = make_float4(0.f, 0.f, 0.f, 0.f);
            if (row < NN) {
                if constexpr (sizeof(XT) == 4) {
                    xv = *(const float4*)&((const float*)X)[(size_t)row * DD + c4];
                } else {
                    ushort4 xb = *(const ushort4*)&((const unsigned short*)X)[(size_t)row * DD + c4];
                    xv = make_float4(bf2f(xb.x), bf2f(xb.y), bf2f(xb.z), bf2f(xb.w));
                }
            }
            if (LN) {
                xv.x = fmaxf((xv.x - mean) * inv * lw4.x + lb4.x, 0.f);
                xv.y = fmaxf((xv.y - mean) * inv * lw4.y + lb4.y, 0.f);
                xv.z = fmaxf((xv.z - mean) * inv * lw4.z + lb4.z, 0.f);
                xv.w = fmaxf((xv.w - mean) * inv * lw4.w + lb4.w, 0.f);
            }
            uint2 pk = make_uint2(pack2(xv.x, xv.y), pack2(xv.z, xv.w));
            *(uint2*)&As[r * 136 + c4] = pk;
        }
    }
    __syncthreads();

    int lane = tid & 63, w = tid >> 6;    // 8 waves
    int rg = w & 3, cg = w >> 2;          // row-group, col-group
    int l15 = lane & 15, quad = lane >> 4;
    f32x4 acc[4];
    #pragma unroll
    for (int t = 0; t < 4; ++t) acc[t] = 0.f;
    const unsigned short* Arow = As + (rg * 16 + l15) * 136 + quad * 8;
    const unsigned short* Brow = Bt + l15 * 136 + quad * 8;
    #pragma unroll
    for (int ks = 0; ks < 4; ++ks) {
        short8 a = *(const short8*)(Arow + ks * 32);
        #pragma unroll
        for (int tt = 0; tt < 4; ++tt) {
            short8 b = *(const short8*)(Brow + (cg * 4 + tt) * 16 * 136 + ks * 32);
            acc[tt] = __builtin_amdgcn_mfma_f32_16x16x32_bf16(a, b, acc[tt], 0, 0, 0);
        }
    }
    __syncthreads();   // all waves done reading Bt/As; Cs may overwrite

    #pragma unroll
    for (int tt = 0; tt < 4; ++tt)
        #pragma unroll
        for (int r = 0; r < 4; ++r)
            Cs[(rg * 16 + quad * 4 + r) * 132 + (cg * 4 + tt) * 16 + l15] = acc[tt][r];

    // attention dots: wave covers cols (cg*4+tt)*16+l15; for H=2 head == cg exactly
    float ds[4] = {0.f, 0.f, 0.f, 0.f}, dd[4] = {0.f, 0.f, 0.f, 0.f};
    #pragma unroll
    for (int tt = 0; tt < 4; ++tt) {
        int cc = (cg * 4 + tt) * 16 + l15;
        float as_ = att_s[cc], ad_ = att_d[cc];
        #pragma unroll
        for (int r = 0; r < 4; ++r) {
            ds[r] = fmaf(acc[tt][r], as_, ds[r]);
            dd[r] = fmaf(acc[tt][r], ad_, dd[r]);
        }
    }
    #pragma unroll
    for (int off = 1; off < 16; off <<= 1) {
        #pragma unroll
        for (int r = 0; r < 4; ++r) {
            ds[r] += __shfl_xor(ds[r], off);
            dd[r] += __shfl_xor(dd[r], off);
        }
    }
    if (l15 == 0) {
        #pragma unroll
        for (int r = 0; r < 4; ++r) {
            int rr = rg * 16 + quad * 4 + r;
            int row = row0 + rr;
            if (H == 2) {
                if (row < NN) {
                    a_src[row * 2 + cg] = ds[r];
                    a_dst[row * 2 + cg] = dd[r];
                }
            } else {
                psum[cg * 64 + rr] = ds[r];
                psum[128 + cg * 64 + rr] = dd[r];
            }
        }
    }
    __syncthreads();

    if (H == 1 && tid < 64) {
        int row = row0 + tid;
        if (row < NN) {
            a_src[row] = psum[tid] + psum[64 + tid];
            a_dst[row] = psum[128 + tid] + psum[192 + tid];
        }
    }

    // ---- coalesced readout: float4 LDS reads, ushort4 global stores ----
    {
        int sub = tid & 31, rq = tid >> 5;
        int c4 = sub * 4;
        unsigned short* Hp = (unsigned short*)Hout;
        #pragma unroll
        for (int i = 0; i < 4; ++i) {
            int r = i * 16 + rq;
            int row = row0 + r;
            if (row < NN) {
                float4 cv = *(const float4*)&Cs[r * 132 + c4];
                ushort4 pk;
                pk.x = f2bf(cv.x); pk.y = f2bf(cv.y);
                pk.z = f2bf(cv.z); pk.w = f2bf(cv.w);
                *(ushort4*)&Hp[(size_t)row * DD + c4] = pk;
            }
        }
    }
}

// ============ GAT softmax + aggregate: HALF-WAVE PER NODE, shuffle broadcast ==============
// pstats: ONE float2 per BLOCK (8-node partial) -> tiny reduce kernel after.
template <int H, typename OT>
__global__ __launch_bounds__(256) void gat_agg(const int* __restrict__ row_ptr,
                                               const unsigned* __restrict__ col,
                                               const bf16* __restrict__ Hin,
                                               const float* __restrict__ a_src,
                                               const float* __restrict__ a_dst,
                                               const float* __restrict__ bias,
                                               OT* __restrict__ Out,
                                               float2* __restrict__ pstats) {
    int tid = threadIdx.x;
    int sl = tid & 31;
    int hw = tid >> 5;
    int n = blockIdx.x * 8 + hw;
    int c0 = sl * 4;
    const int head4 = (H == 2) ? (sl >> 4) : 0;

    int beg = row_ptr[n], end = row_ptr[n + 1];
    int deg = end - beg;

    float ad0 = a_dst[n * H + 0];
    float ad1 = (H == 2) ? a_dst[n * H + 1] : 0.f;
    const ushort* Hp = (const ushort*)Hin + c0;

    float acc[4] = {0.f, 0.f, 0.f, 0.f};
    float dl0 = 0.f, dl1 = 0.f;

    for (int base = 0; base < deg; base += 32) {
        int ecnt = min(32, deg - base);
        int sv = 0; float w0v = 0.f, w1v = 0.f;
        if (sl < ecnt) {
            sv = (int)(col[beg + base + sl] & 0xffffu);
            if (H == 2) {
                float2 av = *(const float2*)&a_src[sv * 2];
                float e0 = av.x + ad0; e0 = (e0 > 0.f) ? e0 : NEG * e0;
                float e1 = av.y + ad1; e1 = (e1 > 0.f) ? e1 : NEG * e1;
                w0v = __expf(e0); w1v = __expf(e1);
                dl0 += w0v; dl1 += w1v;
            } else {
                float e0 = a_src[sv] + ad0; e0 = (e0 > 0.f) ? e0 : NEG * e0;
                w0v = __expf(e0);
                dl0 += w0v;
            }
        }
        int j = 0;
        for (; j + 7 < ecnt; j += 8) {
            int s[8]; float ww[8];
            uint2 h[8];
            #pragma unroll
            for (int u = 0; u < 8; ++u) {
                s[u] = __shfl(sv, j + u, 32);
                if (H == 2) {
                    float a0 = __shfl(w0v, j + u, 32), b0 = __shfl(w1v, j + u, 32);
                    ww[u] = head4 ? b0 : a0;
                } else {
                    ww[u] = __shfl(w0v, j + u, 32);
                }
            }
            #pragma unroll
            for (int u = 0; u < 8; ++u) h[u] = *(const uint2*)(Hp + (size_t)s[u] * DD);
            #pragma unroll
            for (int u = 0; u < 8; ++u) {
                acc[0] = fmaf(ww[u], bflo(h[u].x), acc[0]);
                acc[1] = fmaf(ww[u], bfhi(h[u].x), acc[1]);
                acc[2] = fmaf(ww[u], bflo(h[u].y), acc[2]);
                acc[3] = fmaf(ww[u], bfhi(h[u].y), acc[3]);
            }
        }
        for (; j < ecnt; ++j) {
            int s = __shfl(sv, j, 32);
            float w;
            if (H == 2) {
                float a0 = __shfl(w0v, j, 32), b0 = __shfl(w1v, j, 32);
                w = head4 ? b0 : a0;
            } else {
                w = __shfl(w0v, j, 32);
            }
            uint2 hv = *(const uint2*)(Hp + (size_t)s * DD);
            acc[0] = fmaf(w, bflo(hv.x), acc[0]); acc[1] = fmaf(w, bfhi(hv.x), acc[1]);
            acc[2] = fmaf(w, bflo(hv.y), acc[2]); acc[3] = fmaf(w, bfhi(hv.y), acc[3]);
        }
    }

    #pragma unroll
    for (int off = 1; off < 32; off <<= 1) {
        dl0 += __shfl_xor(dl0, off);
        if (H == 2) dl1 += __shfl_xor(dl1, off);
    }

    // implicit self-loop
    float e0 = a_src[n * H + 0] + ad0; e0 = (e0 > 0.f) ? e0 : NEG * e0;
    float ws0 = __expf(e0);
    float ws1 = 0.f;
    if (H == 2) {
        float e1 = a_src[n * H + 1] + ad1; e1 = (e1 > 0.f) ? e1 : NEG * e1;
        ws1 = __expf(e1);
    }
    float den = (H == 2 && head4) ? (dl1 + ws1) : (dl0 + ws0);
    float wself = (H == 2 && head4) ? ws1 : ws0;
    float rinv = 1.f / (den + 1e-16f);
    uint2 hs = *(const uint2*)(Hp + (size_t)n * DD);
    float4 bi = *(const float4*)&bias[c0];
    float4 o;
    o.x = fmaf(wself, bflo(hs.x), acc[0]) * rinv + bi.x;
    o.y = fmaf(wself, bfhi(hs.x), acc[1]) * rinv + bi.y;
    o.z = fmaf(wself, bflo(hs.y), acc[2]) * rinv + bi.z;
    o.w = fmaf(wself, bfhi(hs.y), acc[3]) * rinv + bi.w;
    store4(Out, (size_t)n * DD + c0, o);

    // LN partials: per half-wave -> LDS -> one float2 per block
    float t1 = o.x + o.y + o.z + o.w;
    float t2 = o.x * o.x + o.y * o.y + o.z * o.z + o.w * o.w;
    #pragma unroll
    for (int off = 1; off < 32; off <<= 1) {
        t1 += __shfl_xor(t1, off);
        t2 += __shfl_xor(t2, off);
    }
    __shared__ float2 ps[8];
    if (sl == 0) ps[hw] = make_float2(t1, t2);
    __syncthreads();
    if (tid == 0) {
        float a = 0.f, b = 0.f;
        #pragma unroll
        for (int k = 0; k < 8; ++k) { a += ps[k].x; b += ps[k].y; }
        pstats[blockIdx.x] = make_float2(a, b);
    }
}

// -------- deterministic single-block reduce of per-BLOCK LN partials (AB entries) ---------
__global__ __launch_bounds__(1024) void reduce_stats_kernel(const float2* __restrict__ pstats,
                                                            double* __restrict__ stats) {
    int tid = threadIdx.x, lane = tid & 63, wv = tid >> 6;
    double s1 = 0.0, s2 = 0.0;
    for (int i = tid; i < AB; i += 1024) {
        float2 v = pstats[i];
        s1 += (double)v.x; s2 += (double)v.y;
    }
    for (int off = 32; off; off >>= 1) {
        s1 += __shfl_xor(s1, off);
        s2 += __shfl_xor(s2, off);
    }
    __shared__ double w1[16], w2[16];
    if (lane == 0) { w1[wv] = s1; w2[wv] = s2; }
    __syncthreads();
    if (tid == 0) {
        double a = 0.0, b = 0.0;
        for (int i = 0; i < 16; ++i) { a += w1[i]; b += w2[i]; }
        stats[0] = a; stats[1] = b;
    }
}

// ======== SimpleConv(mean) + LN2 affine + residual + relu: half-wave per node =============
__global__ __launch_bounds__(256) void simpleconv_kernel(const int* __restrict__ row_ptr,
                                                         const unsigned* __restrict__ col,
                                                         const bf16* __restrict__ Hin,
                                                         const float* __restrict__ X,
                                                         const double* __restrict__ stats,
                                                         const float* __restrict__ lnw,
                                                         const float* __restrict__ lnb,
                                                         float* __restrict__ Out) {
    int tid = threadIdx.x;
    int sl = tid & 31;
    int n = blockIdx.x * 8 + (tid >> 5);
    int c0 = sl * 4;
    int beg = row_ptr[n], end = row_ptr[n + 1];
    int deg = end - beg;
    const ushort* Hp = (const ushort*)Hin + c0;

    float acc[4] = {0.f, 0.f, 0.f, 0.f};
    for (int base = 0; base < deg; base += 32) {
        int ecnt = min(32, deg - base);
        int sv = 0;
        if (sl < ecnt) sv = (int)(col[beg + base + sl] & 0xffffu);
        int j = 0;
        for (; j + 7 < ecnt; j += 8) {
            int s[8]; uint2 h[8];
            #pragma unroll
            for (int u = 0; u < 8; ++u) s[u] = __shfl(sv, j + u, 32);
            #pragma unroll
            for (int u = 0; u < 8; ++u) h[u] = *(const uint2*)(Hp + (size_t)s[u] * DD);
            #pragma unroll
            for (int u = 0; u < 8; ++u) {
                acc[0] += bflo(h[u].x); acc[1] += bfhi(h[u].x);
                acc[2] += bflo(h[u].y); acc[3] += bfhi(h[u].y);
            }
        }
        for (; j < ecnt; ++j) {
            int s = __shfl(sv, j, 32);
            uint2 hv = *(const uint2*)(Hp + (size_t)s * DD);
            acc[0] += bflo(hv.x); acc[1] += bfhi(hv.x);
            acc[2] += bflo(hv.y); acc[3] += bfhi(hv.y);
        }
    }

    const double M = (double)NN * DD;
    double mean_d = stats[0] / M;
    double var_d = stats[1] / M - mean_d * mean_d;
    float mean2 = (float)mean_d;
    float inv2 = rsqrtf((float)var_d + EPSL);
    float rc = 1.f / (float)((deg > 0) ? deg : 1);
    float4 xr = *(const float4*)&X[(size_t)n * DD + c0];
    float4 o;
    if (deg > 0) {
        float4 lw = *(const float4*)&lnw[c0];
        float4 lb = *(const float4*)&lnb[c0];
        o.x = (acc[0] * rc - mean2) * inv2 * lw.x + lb.x;
        o.y = (acc[1] * rc - mean2) * inv2 * lw.y + lb.y;
        o.z = (acc[2] * rc - mean2) * inv2 * lw.z + lb.z;
        o.w = (acc[3] * rc - mean2) * inv2 * lw.w + lb.w;
    } else {
        o.x = o.y = o.z = o.w = 0.f;
    }
    o.x = fmaxf(o.x + xr.x, 0.f);
    o.y = fmaxf(o.y + xr.y, 0.f);
    o.z = fmaxf(o.z + xr.z, 0.f);
    o.w = fmaxf(o.w + xr.w, 0.f);
    *(float4*)&Out[(size_t)n * DD + c0] = o;
}

extern "C" void kernel_launch(void* const* d_in, const int* in_sizes, int n_in,
                              void* d_out, int out_size, void* d_ws, size_t ws_size,
                              hipStream_t stream) {
    const float* x    = (const float*)d_in[0];
    const int*   ei   = (const int*)d_in[1];
    const float* W1   = (const float*)d_in[2];
    const float* as1  = (const float*)d_in[3];
    const float* ad1  = (const float*)d_in[4];
    const float* b1   = (const float*)d_in[5];
    const float* ln1w = (const float*)d_in[6];
    const float* ln1b = (const float*)d_in[7];
    const float* W2   = (const float*)d_in[8];
    const float* as2  = (const float*)d_in[9];
    const float* ad2  = (const float*)d_in[10];
    const float* b2   = (const float*)d_in[11];
    const float* ln2w = (const float*)d_in[12];
    const float* ln2b = (const float*)d_in[13];
    float* out = (float*)d_out;

    char* p = (char*)d_ws;
    auto alloc = [&](size_t bytes) {
        void* r = (void*)p;
        p += (bytes + 255) & ~(size_t)255;
        return r;
    };
    unsigned* tmp     = (unsigned*)alloc((size_t)EE * 4);
    unsigned* col     = (unsigned*)alloc((size_t)EE * 4);
    int*      histG   = (int*)alloc((size_t)HM * 4);
    int*      offs    = (int*)alloc((size_t)HM * 4);
    int*      bstart  = (int*)alloc((size_t)(NBKT + 1) * 4);
    int*      row_ptr = (int*)alloc((size_t)(NN + 256) * 4);
    double*   stats1  = (double*)alloc(16);
    double*   stats2  = (double*)alloc(16);
    float2*   pstats  = (float2*)alloc((size_t)AB * 8);
    bf16*     bufA    = (bf16*)alloc((size_t)NN * DD * 2);   // h1, later h2
    bf16*     bufB    = (bf16*)alloc((size_t)NN * DD * 2);   // out1, later out2
    float*    aS1     = (float*)alloc((size_t)NN * 2 * 4);
    float*    aD1     = (float*)alloc((size_t)NN * 2 * 4);
    float*    aS2     = (float*)alloc((size_t)NN * 4);
    float*    aD2     = (float*)alloc((size_t)NN * 4);

    // ---- CSR build (bucket sort, dense writes; no key buffer; row_ptr fused) ----
    hist_kernel<<<NB, 256, 0, stream>>>(ei, histG);
    scan_hist_kernel<<<1, 1024, 0, stream>>>(histG, offs, bstart);
    scatter_pass1_kernel<<<NB, 256, 0, stream>>>(ei, offs, tmp);
    bucket_sort_kernel<<<NBKT, 256, 0, stream>>>(tmp, bstart, col, row_ptr);

    const int GB = (NN + GROWS - 1) / GROWS;   // 782

    // layer 1: GATConv(128 -> 64, heads=2, concat); LN1+relu deferred into next gemm
    gemm_attn<2, false, float><<<GB, 512, 0, stream>>>(x, W1, as1, ad1,
                                                       nullptr, nullptr, nullptr,
                                                       bufA, aS1, aD1);
    gat_agg<2, bf16><<<AB, 256, 0, stream>>>(row_ptr, col, bufA, aS1, aD1, b1, bufB, pstats);
    reduce_stats_kernel<<<1, 1024, 0, stream>>>(pstats, stats1);

    // layer 2: GATConv(128 -> 128, heads=1), input = relu(ln1(out1)) fused into gemm
    gemm_attn<1, true, bf16><<<GB, 512, 0, stream>>>(bufB, W2, as2, ad2,
                                                     stats1, ln1w, ln1b,
                                                     bufA, aS2, aD2);
    gat_agg<1, bf16><<<AB, 256, 0, stream>>>(row_ptr, col, bufA, aS2, aD2, b2, bufB, pstats);
    reduce_stats_kernel<<<1, 1024, 0, stream>>>(pstats, stats2);

    // SimpleConv mean over original edges + LN2 affine + residual + relu (fused)
    simpleconv_kernel<<<AB, 256, 0, stream>>>(row_ptr, col, bufB, x,
                                              stats2, ln2w, ln2b, out);
}